// Round 8
// baseline (192.616 us; speedup 1.0000x reference)
//
#include <hip/hip_runtime.h>
#include <hip/hip_bf16.h>
#include <math.h>

// Problem constants (fixed by the reference file)
constexpr int B_   = 2;
constexpr int N_   = 2048;   // T*HS*WS = 8*16*16
constexpr int D_   = 1024;
constexpr int NH_  = 16;
constexpr int NKV_ = 4;
constexpr int HD_  = 64;
constexpr int BN_  = 4096;   // B_*N_
constexpr int KVD_ = NKV_ * HD_;  // 256
constexpr float EPS_ = 1e-6f;
constexpr float THETA_ = 10000.0f;
constexpr float LOG2E_ = 1.4426950408889634f;

typedef _Float16 half8v __attribute__((ext_vector_type(8)));
typedef _Float16 half4v __attribute__((ext_vector_type(4)));
typedef unsigned short ushort8v __attribute__((ext_vector_type(8)));
typedef float f32x4 __attribute__((ext_vector_type(4)));

static __device__ __forceinline__ unsigned short f2h(float f) {
  union { _Float16 h; unsigned short u; } v; v.h = (_Float16)f; return v.u;
}
static __device__ __forceinline__ float h2f(unsigned short u) {
  union { unsigned short u; _Float16 h; } v; v.u = u; return (float)v.h;
}

// Hardware 2^x. q is pre-scaled by log2(e) so exp(s_raw) == exp2(s).
#if __has_builtin(__builtin_amdgcn_exp2f)
#define EXP2F(x) __builtin_amdgcn_exp2f(x)
#else
#define EXP2F(x) __expf((x) * 0.6931471805599453f)
#endif

// global -> LDS direct DMA, 16 B per lane. LDS dest = wave-uniform base +
// lane*16 (m104). The per-lane GLOBAL address is free, which lets us store an
// XOR-swizzled layout (chunk c of row r lands at slot c^(r&7)) so the b128
// fragment reads are conflict-free without padding.
static __device__ __forceinline__ void dma16(const unsigned short* g,
                                             unsigned short* l) {
  __builtin_amdgcn_global_load_lds(
      (const __attribute__((address_space(1))) unsigned int*)g,
      (__attribute__((address_space(3))) unsigned int*)l, 16, 0, 0);
}

// ---------------------------------------------------------------------------
// prep: one launch doing x->f16 cast + all 4 weight transposes (f16; Wo hi/lo
// with x64 pre-scale). Linear block-id partition.
// ---------------------------------------------------------------------------
static __device__ __forceinline__ void wtrans_tile(
    const float* __restrict__ W, int Nw, int K, float scale,
    unsigned short* __restrict__ WTh, unsigned short* __restrict__ WTl,
    int bx, int by, bool lo)
{
  __shared__ float tile[32][33];
  const int k0 = bx * 32, n0 = by * 32;
  const int c = threadIdx.x & 31, rb = threadIdx.x >> 5;
#pragma unroll
  for (int i = 0; i < 4; ++i) {
    const int r = rb + i * 8;
    tile[r][c] = W[(size_t)(k0 + r) * Nw + n0 + c];
  }
  __syncthreads();
#pragma unroll
  for (int i = 0; i < 4; ++i) {
    const int r = rb + i * 8;
    const float v = tile[c][r] * scale;   // = W[k0+c][n0+r] * scale
    const size_t o = (size_t)(n0 + r) * K + k0 + c;
    const unsigned short hi = f2h(v);
    WTh[o] = hi;
    if (lo) WTl[o] = f2h(v - h2f(hi));
  }
}

__global__ __launch_bounds__(256) void prep(
    const float* __restrict__ x,
    const float* __restrict__ Wq, const float* __restrict__ Wk,
    const float* __restrict__ Wv, const float* __restrict__ Wo,
    unsigned short* __restrict__ xh,
    unsigned short* __restrict__ WqT, unsigned short* __restrict__ WkT,
    unsigned short* __restrict__ WvT,
    unsigned short* __restrict__ WoTh, unsigned short* __restrict__ WoTl)
{
  const int bid = blockIdx.x;
  if (bid < 2048) {
    const int i = (bid * 256 + threadIdx.x) * 8;
    const float4 v0 = *(const float4*)(x + i);
    const float4 v1 = *(const float4*)(x + i + 4);
    ushort8v o;
    o[0] = f2h(v0.x); o[1] = f2h(v0.y); o[2] = f2h(v0.z); o[3] = f2h(v0.w);
    o[4] = f2h(v1.x); o[5] = f2h(v1.y); o[6] = f2h(v1.z); o[7] = f2h(v1.w);
    *(ushort8v*)(xh + i) = o;
  } else if (bid < 3072) {
    const int l = bid - 2048;
    wtrans_tile(Wq, D_, D_, 1.0f, WqT, nullptr, l & 31, l >> 5, false);
  } else if (bid < 3328) {
    const int l = bid - 3072;
    wtrans_tile(Wk, KVD_, D_, 1.0f, WkT, nullptr, l & 31, l >> 5, false);
  } else if (bid < 3584) {
    const int l = bid - 3328;
    wtrans_tile(Wv, KVD_, D_, 1.0f, WvT, nullptr, l & 31, l >> 5, false);
  } else {
    const int l = bid - 3584;
    wtrans_tile(Wo, D_, D_, 64.0f, WoTh, WoTl, l & 31, l >> 5, true);
  }
}

// ---------------------------------------------------------------------------
// Fused QKV projection + RMSNorm + 3D RoPE in the epilogue (r5 form).
// 128x64 tile (768 blocks = 3/CU), BK=64. 4 waves all-M. m97-style staging:
// global_load_lds width 16 into XOR-swizzled unpadded LDS.
// Q output carries log2(e) so attention can use hw exp2.
// ---------------------------------------------------------------------------
__global__ __launch_bounds__(256) void gemm_qkv(
    const unsigned short* __restrict__ xh,
    const unsigned short* __restrict__ WqT, const unsigned short* __restrict__ WkT,
    const unsigned short* __restrict__ WvT,
    const float* __restrict__ bq, const float* __restrict__ bk, const float* __restrict__ bv,
    const float* __restrict__ qn, const float* __restrict__ kn,
    unsigned short* __restrict__ qv, unsigned short* __restrict__ kv,
    unsigned short* __restrict__ vv)
{
  __shared__ unsigned short As[128 * 64];   // swizzled, 16 KB
  __shared__ unsigned short Bs[64 * 64];    // swizzled, 8 KB

  const int y = blockIdx.y;
  const unsigned short* wt; const float* bias; unsigned short* outp; int opitch, col0, mode;
  if (y < 16)      { wt = WqT + (size_t)y * 64 * D_;        bias = bq + y * 64;        outp = qv; opitch = D_;   col0 = y * 64;        mode = 0; }
  else if (y < 20) { wt = WkT + (size_t)(y - 16) * 64 * D_; bias = bk + (y - 16) * 64; outp = kv; opitch = KVD_; col0 = (y - 16) * 64; mode = 1; }
  else             { wt = WvT + (size_t)(y - 20) * 64 * D_; bias = bv + (y - 20) * 64; outp = vv; opitch = KVD_; col0 = (y - 20) * 64; mode = 2; }

  const int bm = blockIdx.x * 128;
  const int tid = threadIdx.x;
  const int w = tid >> 6, lane = tid & 63, quad = lane >> 4, l16 = lane & 15;
  const int lr = lane >> 3;          // staged sub-row 0..7
  const int gc = (lane & 7) ^ lr;    // swizzled source chunk
  const int sw = l16 & 7;            // frag-read swizzle selector

  const unsigned short* gA = xh + (size_t)(bm + w * 8 + lr) * D_ + gc * 8;
  const unsigned short* gB = wt + (size_t)(w * 8 + lr) * D_ + gc * 8;

  f32x4 acc[2][4];
#pragma unroll
  for (int i = 0; i < 2; ++i)
#pragma unroll
    for (int j = 0; j < 4; ++j) acc[i][j] = (f32x4){0.f, 0.f, 0.f, 0.f};

  for (int k0 = 0; k0 < D_; k0 += 64) {
    __syncthreads();
#pragma unroll
    for (int rd = 0; rd < 4; ++rd)
      dma16(gA + (size_t)rd * 32 * D_ + k0, &As[rd * 2048 + w * 512]);
#pragma unroll
    for (int rd = 0; rd < 2; ++rd)
      dma16(gB + (size_t)rd * 32 * D_ + k0, &Bs[rd * 2048 + w * 512]);
    __syncthreads();

#pragma unroll
    for (int kk = 0; kk < 2; ++kk) {
      half8v fa[2], fb[4];
#pragma unroll
      for (int mb = 0; mb < 2; ++mb)
        fa[mb] = *(const half8v*)&As[(w * 32 + mb * 16 + l16) * 64 + ((kk * 4 + quad) ^ sw) * 8];
#pragma unroll
      for (int nb = 0; nb < 4; ++nb)
        fb[nb] = *(const half8v*)&Bs[(nb * 16 + l16) * 64 + ((kk * 4 + quad) ^ sw) * 8];
#pragma unroll
      for (int mb = 0; mb < 2; ++mb)
#pragma unroll
        for (int nb = 0; nb < 4; ++nb)
          acc[mb][nb] = __builtin_amdgcn_mfma_f32_16x16x32_f16(fa[mb], fb[nb], acc[mb][nb], 0, 0, 0);
    }
  }

  float bsv[4];
#pragma unroll
  for (int nb = 0; nb < 4; ++nb) bsv[nb] = bias[nb * 16 + l16];

  if (mode == 2) {   // V: bias + cast only
#pragma unroll
    for (int mb = 0; mb < 2; ++mb)
#pragma unroll
      for (int nb = 0; nb < 4; ++nb)
#pragma unroll
        for (int r = 0; r < 4; ++r) {
          const int row = bm + w * 32 + mb * 16 + quad * 4 + r;
          outp[(size_t)row * opitch + col0 + nb * 16 + l16] = f2h(acc[mb][nb][r] + bsv[nb]);
        }
    return;
  }

  // Q/K: RMSNorm (+learned w) + factored 3D RoPE, fp32 pre-rounding.
  const float* nwp = (mode == 0) ? qn : kn;
  float wv[4];
#pragma unroll
  for (int nb = 0; nb < 4; ++nb) wv[nb] = nwp[nb * 16 + l16];
  const float f_th = __powf(THETA_, -(float)(l16 & 7) / 8.0f);   // t/h segs, dd=16
  const float f_w  = __powf(THETA_, -(float)l16 / 16.0f);        // w seg,  dd=32
  const float oscale = (mode == 0) ? 0.125f * LOG2E_ : 1.0f;     // attn scale * log2e
  const bool first8 = (l16 & 8) == 0;

  float snw[4], csw[4];
#pragma unroll
  for (int r = 0; r < 4; ++r)
    __sincosf((float)(quad * 4 + r) * f_w, &snw[r], &csw[r]);

#pragma unroll
  for (int mb = 0; mb < 2; ++mb) {
    const int nbase = (bm + w * 32 + mb * 16) & (N_ - 1);
    float snt, cst, snh, csh;
    __sincosf((float)(nbase >> 8) * f_th, &snt, &cst);
    __sincosf((float)((nbase >> 4) & 15) * f_th, &snh, &csh);
#pragma unroll
    for (int r = 0; r < 4; ++r) {
      float v[4];
      float ss = 0.f;
#pragma unroll
      for (int nb = 0; nb < 4; ++nb) { v[nb] = acc[mb][nb][r] + bsv[nb]; ss += v[nb] * v[nb]; }
      ss += __shfl_xor(ss, 1, 64);
      ss += __shfl_xor(ss, 2, 64);
      ss += __shfl_xor(ss, 4, 64);
      ss += __shfl_xor(ss, 8, 64);
      const float rs = rsqrtf(ss * (1.0f / 64.0f) + EPS_);
#pragma unroll
      for (int nb = 0; nb < 4; ++nb) v[nb] *= rs * wv[nb];

      const float p0 = __shfl_xor(v[0], 8, 64);
      const float p1 = __shfl_xor(v[1], 8, 64);
      const float o0 = v[0] * cst + (first8 ? -p0 : p0) * snt;
      const float o1 = v[1] * csh + (first8 ? -p1 : p1) * snh;
      const float o2 = v[2] * csw[r] - v[3] * snw[r];
      const float o3 = v[3] * csw[r] + v[2] * snw[r];

      const int row = bm + w * 32 + mb * 16 + quad * 4 + r;
      const size_t ob = (size_t)row * opitch + col0 + l16;
      outp[ob]      = f2h(o0 * oscale);
      outp[ob + 16] = f2h(o1 * oscale);
      outp[ob + 32] = f2h(o2 * oscale);
      outp[ob + 48] = f2h(o3 * oscale);
    }
  }
}

// ---------------------------------------------------------------------------
// Output projection (r5 form): A = O (single f16), B = 64*Wo^T f16 hi+lo.
// 128x64 tile (512 blocks), BK=64, 4 waves all-M. Same DMA+swizzle staging.
// ---------------------------------------------------------------------------
__global__ __launch_bounds__(256) void gemm_o(
    const unsigned short* __restrict__ ag,
    const unsigned short* __restrict__ WTh, const unsigned short* __restrict__ WTl,
    const float* __restrict__ bo, float* __restrict__ out)
{
  __shared__ unsigned short As[128 * 64];
  __shared__ unsigned short Bh[64 * 64], Bl[64 * 64];

  const int bm = blockIdx.x * 128, bn = blockIdx.y * 64;
  const int tid = threadIdx.x;
  const int w = tid >> 6, lane = tid & 63, quad = lane >> 4, l16 = lane & 15;
  const int lr = lane >> 3;
  const int gc = (lane & 7) ^ lr;
  const int sw = l16 & 7;

  const unsigned short* gA  = ag  + (size_t)(bm + w * 8 + lr) * D_ + gc * 8;
  const unsigned short* gBh = WTh + (size_t)(bn + w * 8 + lr) * D_ + gc * 8;
  const unsigned short* gBl = WTl + (size_t)(bn + w * 8 + lr) * D_ + gc * 8;

  f32x4 acc[2][4];
#pragma unroll
  for (int i = 0; i < 2; ++i)
#pragma unroll
    for (int j = 0; j < 4; ++j) acc[i][j] = (f32x4){0.f, 0.f, 0.f, 0.f};

  for (int k0 = 0; k0 < D_; k0 += 64) {
    __syncthreads();
#pragma unroll
    for (int rd = 0; rd < 4; ++rd)
      dma16(gA + (size_t)rd * 32 * D_ + k0, &As[rd * 2048 + w * 512]);
#pragma unroll
    for (int rd = 0; rd < 2; ++rd) {
      dma16(gBh + (size_t)rd * 32 * D_ + k0, &Bh[rd * 2048 + w * 512]);
      dma16(gBl + (size_t)rd * 32 * D_ + k0, &Bl[rd * 2048 + w * 512]);
    }
    __syncthreads();

#pragma unroll
    for (int kk = 0; kk < 2; ++kk) {
      half8v fa[2], fbh[4], fbl[4];
#pragma unroll
      for (int mb = 0; mb < 2; ++mb)
        fa[mb] = *(const half8v*)&As[(w * 32 + mb * 16 + l16) * 64 + ((kk * 4 + quad) ^ sw) * 8];
#pragma unroll
      for (int nb = 0; nb < 4; ++nb) {
        const int ro = (nb * 16 + l16) * 64 + ((kk * 4 + quad) ^ sw) * 8;
        fbh[nb] = *(const half8v*)&Bh[ro];
        fbl[nb] = *(const half8v*)&Bl[ro];
      }
#pragma unroll
      for (int mb = 0; mb < 2; ++mb)
#pragma unroll
        for (int nb = 0; nb < 4; ++nb) {
          acc[mb][nb] = __builtin_amdgcn_mfma_f32_16x16x32_f16(fa[mb], fbl[nb], acc[mb][nb], 0, 0, 0);
          acc[mb][nb] = __builtin_amdgcn_mfma_f32_16x16x32_f16(fa[mb], fbh[nb], acc[mb][nb], 0, 0, 0);
        }
    }
  }

  float bsv[4];
#pragma unroll
  for (int nb = 0; nb < 4; ++nb) bsv[nb] = bo[bn + nb * 16 + l16];
#pragma unroll
  for (int mb = 0; mb < 2; ++mb)
#pragma unroll
    for (int nb = 0; nb < 4; ++nb)
#pragma unroll
      for (int r = 0; r < 4; ++r) {
        const int row = bm + w * 32 + mb * 16 + quad * 4 + r;
        const int col = bn + nb * 16 + l16;
        out[(size_t)row * D_ + col] = acc[mb][nb][r] * 0.015625f + bsv[nb];
      }
}

// ---------------------------------------------------------------------------
// MFMA flash attention — KV-SPLIT P-in-register version.
// The r5-r7 structure was grid-capped at 256 blocks = 1 block/CU = 2 waves/
// SIMD (latency-bound: MfmaUtil 25 + VALU 31 + LDS ~33, nothing saturated).
// Split the key range in 2: grid = 16 qt x 16 h x 2 b x 2 ks = 1024 blocks,
// 256 thr (4 waves x 32 q-rows, qb=2 kept), 64-key tiles -> LDS 32 KB ->
// __launch_bounds__(256,3): 3 blocks/CU = 3 waves/SIMD (+50% hiding), VGPR
// cap 170 (no r4 spill trap). Each block writes NORMALIZED partial O (f16,
// bounded by max|v| so f16-safe) and its denominator l; a cheap combine pass
// merges: O = (l0*O0 + l1*O1)/(l0+l1). Exact for the no-max softmax.
// ---------------------------------------------------------------------------
__global__ __launch_bounds__(256, 3) void attn_mfma(
    const unsigned short* __restrict__ qg,
    const unsigned short* __restrict__ kg,
    const unsigned short* __restrict__ vg,
    unsigned short* __restrict__ po,   // [2][4096][1024] f16 normalized partials
    float* __restrict__ pl)            // [2][4096][16] denominators
{
  __shared__ unsigned short Ks[2][64 * 64];   // swizzled, 2x8 KB
  __shared__ unsigned short Vt[2][64][64];    // [dim][key'-swizzled], 2x8 KB

  const int bid = blockIdx.x;
  const int qt  = bid & 15;          // 16 q-tiles of 128 rows
  const int h   = (bid >> 4) & 15;
  const int b   = (bid >> 8) & 1;
  const int ks  = bid >> 9;          // KV half: keys [ks*1024, ks*1024+1024)
  const int kvh = h >> 2;            // GQA: q-head h -> kv-head h/4

  const int tid  = threadIdx.x;
  const int w    = tid >> 6;         // 0..3
  const int lane = tid & 63;
  const int quad = lane >> 4;
  const int l16  = lane & 15;
  const int lr = lane >> 3;
  const int gc = (lane & 7) ^ lr;
  const int sw = l16 & 7;

  // Q frags (B-operand: lane l16 = q-row, 8 dims at quad*8 / 32+quad*8).
  half8v aq[2][2];
#pragma unroll
  for (int qb = 0; qb < 2; ++qb) {
    const int qrow = qt * 128 + w * 32 + qb * 16 + l16;
    const unsigned short* qptr =
        qg + ((size_t)(b * N_ + qrow) * D_) + h * HD_ + quad * 8;
    aq[qb][0] = *(const half8v*)(qptr);
    aq[qb][1] = *(const half8v*)(qptr + 32);
  }

  // O^T accumulators: o_[qb][nb][r] = O[dim=nb*16+quad*4+r][qrow(l16)]
  f32x4 o_[2][4];
  float lrow[2] = {0.f, 0.f};        // per-lane softmax denom (q-row local)
#pragma unroll
  for (int qb = 0; qb < 2; ++qb)
#pragma unroll
    for (int i = 0; i < 4; ++i) o_[qb][i] = (f32x4){0.f, 0.f, 0.f, 0.f};

  // K DMA source: 2 dma16/wave x 4 waves cover 64 rows (row = rd*32 + w*8 + lr)
  const unsigned short* gK =
      kg + ((size_t)(b * N_ + ks * 1024) + w * 8 + lr) * KVD_ + kvh * HD_ + gc * 8;

  // V staging with the P-frag key' permutation + chunk-XOR swizzle.
  //   within-tile key K (bits k5..k0) -> pos = k5*32 + (k3k2)*8 + k4*4 + k1k0
  //   chunk (pos>>3) of dim-row r stored at chunk^(r&7).
  // Thread (vp, vs): key pair (2vp, 2vp+1), dims 8vs..8vs+7, one u32/dim.
  const int vp = tid & 31;           // key pair 0..31
  const int vs = tid >> 5;           // dim octet 0..7
  const int vchunk  = ((vp >> 4) & 1) * 4 + ((vp >> 1) & 3);   // 0..7
  const int vwithin = ((vp >> 3) & 1) * 4 + (vp & 1) * 2;      // even 0..6
  const unsigned short* gV =
      vg + (size_t)(b * N_ + ks * 1024 + 2 * vp) * KVD_ + kvh * HD_ + 8 * vs;

  // ---- prologue: stage tile 0, prefetch V tile 1 ----
#pragma unroll
  for (int rd = 0; rd < 2; ++rd)
    dma16(gK + (size_t)(rd * 32) * KVD_, &Ks[0][rd * 2048 + w * 512]);
  ushort8v va0 = *(const ushort8v*)(gV);
  ushort8v va1 = *(const ushort8v*)(gV + KVD_);
#pragma unroll
  for (int i = 0; i < 8; ++i)
    *(unsigned int*)&Vt[0][8 * vs + i][((vchunk ^ i) << 3) + vwithin] =
        (unsigned int)va0[i] | ((unsigned int)va1[i] << 16);
  {
    const unsigned short* p = gV + (size_t)64 * KVD_;
    va0 = *(const ushort8v*)(p);
    va1 = *(const ushort8v*)(p + KVD_);
  }
  __syncthreads();

  for (int kt = 0; kt < 16; ++kt) {
    const int cur = kt & 1;
    // stage tile kt+1; DMA/ds_writes drain at the end-of-loop barrier.
    if (kt < 15) {
#pragma unroll
      for (int rd = 0; rd < 2; ++rd)
        dma16(gK + (size_t)((kt + 1) * 64 + rd * 32) * KVD_,
              &Ks[cur ^ 1][rd * 2048 + w * 512]);
#pragma unroll
      for (int i = 0; i < 8; ++i)
        *(unsigned int*)&Vt[cur ^ 1][8 * vs + i][((vchunk ^ i) << 3) + vwithin] =
            (unsigned int)va0[i] | ((unsigned int)va1[i] << 16);
      if (kt < 14) {
        const unsigned short* p = gV + (size_t)(kt + 2) * 64 * KVD_;
        va0 = *(const ushort8v*)(p);
        va1 = *(const ushort8v*)(p + KVD_);
      }
    }

    // ---- compute tile kt (64 keys) from Ks[cur], Vt[cur] ----
    // S^T = K·Q^T : lane holds P[key=nb*16+quad*4+r][qrow=l16]
    f32x4 s[2][4];
    __builtin_amdgcn_s_setprio(1);
#pragma unroll
    for (int nb = 0; nb < 4; ++nb) {
      const int kr = (nb * 16 + l16) * 64;
      const half8v b0 = *(const half8v*)&Ks[cur][kr + (quad ^ sw) * 8];
      const half8v b1 = *(const half8v*)&Ks[cur][kr + ((4 + quad) ^ sw) * 8];
#pragma unroll
      for (int qb = 0; qb < 2; ++qb) {
        f32x4 z = (f32x4){0.f, 0.f, 0.f, 0.f};
        z = __builtin_amdgcn_mfma_f32_16x16x32_f16(b0, aq[qb][0], z, 0, 0, 0);
        s[qb][nb] = __builtin_amdgcn_mfma_f32_16x16x32_f16(b1, aq[qb][1], z, 0, 0, 0);
      }
    }
    __builtin_amdgcn_s_setprio(0);

    // exp2 + pack to P-frags in registers (no LDS round-trip).
    // pf[qb][kc][j]: key K = (2kc+(j>>2))*16 + quad*4 + (j&3)
    half8v pf[2][2];
#pragma unroll
    for (int qb = 0; qb < 2; ++qb) {
      float ls = 0.f;
#pragma unroll
      for (int nb = 0; nb < 4; ++nb) {
        const float p0 = EXP2F(s[qb][nb][0]);
        const float p1 = EXP2F(s[qb][nb][1]);
        const float p2 = EXP2F(s[qb][nb][2]);
        const float p3 = EXP2F(s[qb][nb][3]);
        ls += (p0 + p1) + (p2 + p3);
        const int kc = nb >> 1, jo = (nb & 1) * 4;
        pf[qb][kc][jo + 0] = (_Float16)p0;
        pf[qb][kc][jo + 1] = (_Float16)p1;
        pf[qb][kc][jo + 2] = (_Float16)p2;
        pf[qb][kc][jo + 3] = (_Float16)p3;
      }
      lrow[qb] += ls;
    }

    // O^T += V^T · P^T ; V-frags shared across both q-subtiles
    __builtin_amdgcn_s_setprio(1);
#pragma unroll
    for (int kc = 0; kc < 2; ++kc)
#pragma unroll
      for (int nb = 0; nb < 4; ++nb) {
        const half8v bv =
            *(const half8v*)&Vt[cur][nb * 16 + l16][((kc * 4 + quad) ^ sw) * 8];
#pragma unroll
        for (int qb = 0; qb < 2; ++qb)
          o_[qb][nb] = __builtin_amdgcn_mfma_f32_16x16x32_f16(bv, pf[qb][kc], o_[qb][nb], 0, 0, 0);
      }
    __builtin_amdgcn_s_setprio(0);
    __syncthreads();
  }

  // epilogue: denom reduce across quads, write normalized partial + denom
#pragma unroll
  for (int qb = 0; qb < 2; ++qb) {
    float l = lrow[qb];
    l += __shfl_xor(l, 16, 64);
    l += __shfl_xor(l, 32, 64);
    const float inv = 1.0f / l;
    const int qrow = qt * 128 + w * 32 + qb * 16 + l16;
    const size_t rowg = (size_t)(b * N_ + qrow);
    if (quad == 0) pl[((size_t)ks * 4096 + rowg) * 16 + h] = l;
    const size_t base = ((size_t)ks * 4096 + rowg) * D_ + h * HD_;
#pragma unroll
    for (int nb = 0; nb < 4; ++nb) {
      half4v pk;
#pragma unroll
      for (int r = 0; r < 4; ++r) pk[r] = (_Float16)(o_[qb][nb][r] * inv);
      *(half4v*)&po[base + nb * 16 + quad * 4] = pk;
    }
  }
}

// ---------------------------------------------------------------------------
// combine: O = (l0*O0 + l1*O1)/(l0+l1) over the two KV halves. Streaming,
// ~24 MB traffic (~5 us). Writes og (f16) for gemm_o.
// ---------------------------------------------------------------------------
__global__ __launch_bounds__(256) void combine(
    const unsigned short* __restrict__ po, const float* __restrict__ pl,
    unsigned short* __restrict__ og)
{
  const int idx = blockIdx.x * 256 + threadIdx.x;   // one 8-elem group
  const int e = idx * 8;
  const int row = e >> 10;            // 0..4095
  const int h = (e >> 6) & 15;
  const float l0 = pl[(size_t)row * 16 + h];
  const float l1 = pl[(size_t)(4096 + row) * 16 + h];
  const float inv = 1.0f / (l0 + l1);
  const float w0 = l0 * inv, w1 = l1 * inv;
  const ushort8v a = *(const ushort8v*)(po + e);
  const ushort8v c = *(const ushort8v*)(po + (size_t)4096 * 1024 + e);
  ushort8v o;
#pragma unroll
  for (int i = 0; i < 8; ++i)
    o[i] = f2h(h2f(a[i]) * w0 + h2f(c[i]) * w1);
  *(ushort8v*)(og + e) = o;
}

// ---------------------------------------------------------------------------
extern "C" void kernel_launch(void* const* d_in, const int* in_sizes, int n_in,
                              void* d_out, int out_size, void* d_ws, size_t ws_size,
                              hipStream_t stream) {
  const float* x  = (const float*)d_in[0];
  const float* Wq = (const float*)d_in[1];
  const float* bq = (const float*)d_in[2];
  const float* Wk = (const float*)d_in[3];
  const float* bk = (const float*)d_in[4];
  const float* Wv = (const float*)d_in[5];
  const float* bv = (const float*)d_in[6];
  const float* Wo = (const float*)d_in[7];
  const float* bo = (const float*)d_in[8];
  const float* qn = (const float*)d_in[9];
  const float* kn = (const float*)d_in[10];
  float* out = (float*)d_out;

  // Workspace (u16 units, ~44 MB):
  //  xh(4M) qv(4M) kv(1M) vv(1M) WqT(1M) WkT(.25M) WvT(.25M) WoTh(1M) WoTl(1M)
  //  po(8M u16 = 16 MB) pl(128K f32)
  //  attention combined output og aliases xh (dead after gemm_qkv).
  const size_t M4 = (size_t)BN_ * D_;
  const size_t M1 = (size_t)BN_ * KVD_;
  unsigned short* xh  = (unsigned short*)d_ws;
  unsigned short* qv  = xh + M4;
  unsigned short* kv  = qv + M4;
  unsigned short* vv  = kv + M1;
  unsigned short* WqT = vv + M1;
  unsigned short* WkT = WqT + (size_t)D_ * D_;
  unsigned short* WvT = WkT + (size_t)D_ * KVD_;
  unsigned short* WoTh = WvT + (size_t)D_ * KVD_;
  unsigned short* WoTl = WoTh + (size_t)D_ * D_;
  unsigned short* pov  = WoTl + (size_t)D_ * D_;      // 2 * 4096 * 1024 u16
  float* plv = (float*)(pov + (size_t)2 * 4096 * 1024);  // 2 * 4096 * 16 f32
  unsigned short* og  = xh;   // alias

  const dim3 blk(256);

  // 1) cast + all weight transposes in one launch
  prep<<<dim3(4608), blk, 0, stream>>>(x, Wq, Wk, Wv, Wo, xh, WqT, WkT, WvT, WoTh, WoTl);

  // 2) fused QKV projection + RMSNorm + RoPE (768 blocks)
  gemm_qkv<<<dim3(32, 24), blk, 0, stream>>>(xh, WqT, WkT, WvT, bq, bk, bv, qn, kn, qv, kv, vv);

  // 3) KV-split P-in-register MFMA flash attention (1024 blocks = 3+/CU)
  attn_mfma<<<dim3(1024), blk, 0, stream>>>(qv, kv, vv, pov, plv);

  // 3b) merge the two KV-half partials into og
  combine<<<dim3(2048), blk, 0, stream>>>(pov, plv, og);

  // 4) output projection (512 blocks)
  gemm_o<<<dim3(32, 16), blk, 0, stream>>>(og, WoTh, WoTl, bo, out);
}

// Round 9
// 179.732 us; speedup vs baseline: 1.0717x; 1.0717x over previous
//
#include <hip/hip_runtime.h>
#include <hip/hip_bf16.h>
#include <math.h>

// Problem constants (fixed by the reference file)
constexpr int B_   = 2;
constexpr int N_   = 2048;   // T*HS*WS = 8*16*16
constexpr int D_   = 1024;
constexpr int NH_  = 16;
constexpr int NKV_ = 4;
constexpr int HD_  = 64;
constexpr int BN_  = 4096;   // B_*N_
constexpr int KVD_ = NKV_ * HD_;  // 256
constexpr float EPS_ = 1e-6f;
constexpr float THETA_ = 10000.0f;
constexpr float LOG2E_ = 1.4426950408889634f;

typedef _Float16 half8v __attribute__((ext_vector_type(8)));
typedef _Float16 half4v __attribute__((ext_vector_type(4)));
typedef unsigned short ushort8v __attribute__((ext_vector_type(8)));
typedef float f32x4 __attribute__((ext_vector_type(4)));

static __device__ __forceinline__ unsigned short f2h(float f) {
  union { _Float16 h; unsigned short u; } v; v.h = (_Float16)f; return v.u;
}
static __device__ __forceinline__ float h2f(unsigned short u) {
  union { unsigned short u; _Float16 h; } v; v.u = u; return (float)v.h;
}

// Hardware 2^x. q is pre-scaled by log2(e) so exp(s_raw) == exp2(s).
#if __has_builtin(__builtin_amdgcn_exp2f)
#define EXP2F(x) __builtin_amdgcn_exp2f(x)
#else
#define EXP2F(x) __expf((x) * 0.6931471805599453f)
#endif

// global -> LDS direct DMA, 16 B per lane. LDS dest = wave-uniform base +
// lane*16 (m104). The per-lane GLOBAL address is free, which lets us store an
// XOR-swizzled layout (chunk c of row r lands at slot c^(r&7)) so the b128
// fragment reads are conflict-free without padding.
static __device__ __forceinline__ void dma16(const unsigned short* g,
                                             unsigned short* l) {
  __builtin_amdgcn_global_load_lds(
      (const __attribute__((address_space(1))) unsigned int*)g,
      (__attribute__((address_space(3))) unsigned int*)l, 16, 0, 0);
}

// ---------------------------------------------------------------------------
// prep: one launch doing x->f16 cast + all 4 weight transposes (f16; Wo hi/lo
// with x64 pre-scale). Linear block-id partition.
// ---------------------------------------------------------------------------
static __device__ __forceinline__ void wtrans_tile(
    const float* __restrict__ W, int Nw, int K, float scale,
    unsigned short* __restrict__ WTh, unsigned short* __restrict__ WTl,
    int bx, int by, bool lo)
{
  __shared__ float tile[32][33];
  const int k0 = bx * 32, n0 = by * 32;
  const int c = threadIdx.x & 31, rb = threadIdx.x >> 5;
#pragma unroll
  for (int i = 0; i < 4; ++i) {
    const int r = rb + i * 8;
    tile[r][c] = W[(size_t)(k0 + r) * Nw + n0 + c];
  }
  __syncthreads();
#pragma unroll
  for (int i = 0; i < 4; ++i) {
    const int r = rb + i * 8;
    const float v = tile[c][r] * scale;   // = W[k0+c][n0+r] * scale
    const size_t o = (size_t)(n0 + r) * K + k0 + c;
    const unsigned short hi = f2h(v);
    WTh[o] = hi;
    if (lo) WTl[o] = f2h(v - h2f(hi));
  }
}

__global__ __launch_bounds__(256) void prep(
    const float* __restrict__ x,
    const float* __restrict__ Wq, const float* __restrict__ Wk,
    const float* __restrict__ Wv, const float* __restrict__ Wo,
    unsigned short* __restrict__ xh,
    unsigned short* __restrict__ WqT, unsigned short* __restrict__ WkT,
    unsigned short* __restrict__ WvT,
    unsigned short* __restrict__ WoTh, unsigned short* __restrict__ WoTl)
{
  const int bid = blockIdx.x;
  if (bid < 2048) {
    const int i = (bid * 256 + threadIdx.x) * 8;
    const float4 v0 = *(const float4*)(x + i);
    const float4 v1 = *(const float4*)(x + i + 4);
    ushort8v o;
    o[0] = f2h(v0.x); o[1] = f2h(v0.y); o[2] = f2h(v0.z); o[3] = f2h(v0.w);
    o[4] = f2h(v1.x); o[5] = f2h(v1.y); o[6] = f2h(v1.z); o[7] = f2h(v1.w);
    *(ushort8v*)(xh + i) = o;
  } else if (bid < 3072) {
    const int l = bid - 2048;
    wtrans_tile(Wq, D_, D_, 1.0f, WqT, nullptr, l & 31, l >> 5, false);
  } else if (bid < 3328) {
    const int l = bid - 3072;
    wtrans_tile(Wk, KVD_, D_, 1.0f, WkT, nullptr, l & 31, l >> 5, false);
  } else if (bid < 3584) {
    const int l = bid - 3328;
    wtrans_tile(Wv, KVD_, D_, 1.0f, WvT, nullptr, l & 31, l >> 5, false);
  } else {
    const int l = bid - 3584;
    wtrans_tile(Wo, D_, D_, 64.0f, WoTh, WoTl, l & 31, l >> 5, true);
  }
}

// ---------------------------------------------------------------------------
// Fused QKV projection + RMSNorm + 3D RoPE in the epilogue.
// 128x64 tile (768 blocks = 3/CU), BK=64, 4 waves all-M. NOW: double-buffered
// LDS with COUNTED vmcnt + raw s_barrier (T3+T4). Per K-step: issue stage(s+1)
// DMAs -> s_waitcnt vmcnt(6) (waits stage(s), leaves stage(s+1) IN FLIGHT
// across the barrier) -> s_barrier -> compute(s) -> s_barrier (WAR fence for
// the next overwrite). No vmcnt(0) drain in the main loop — the drain that
// __syncthreads emits is the measured m97-structure stall (learn_hip m218:
// counted-vs-drain0 = +38-73%).
// Q output carries log2(e) so attention can use hw exp2.
// ---------------------------------------------------------------------------
__global__ __launch_bounds__(256) void gemm_qkv(
    const unsigned short* __restrict__ xh,
    const unsigned short* __restrict__ WqT, const unsigned short* __restrict__ WkT,
    const unsigned short* __restrict__ WvT,
    const float* __restrict__ bq, const float* __restrict__ bk, const float* __restrict__ bv,
    const float* __restrict__ qn, const float* __restrict__ kn,
    unsigned short* __restrict__ qv, unsigned short* __restrict__ kv,
    unsigned short* __restrict__ vv)
{
  __shared__ unsigned short As[2][128 * 64];   // swizzled, 2x16 KB
  __shared__ unsigned short Bs[2][64 * 64];    // swizzled, 2x8 KB

  const int y = blockIdx.y;
  const unsigned short* wt; const float* bias; unsigned short* outp; int opitch, col0, mode;
  if (y < 16)      { wt = WqT + (size_t)y * 64 * D_;        bias = bq + y * 64;        outp = qv; opitch = D_;   col0 = y * 64;        mode = 0; }
  else if (y < 20) { wt = WkT + (size_t)(y - 16) * 64 * D_; bias = bk + (y - 16) * 64; outp = kv; opitch = KVD_; col0 = (y - 16) * 64; mode = 1; }
  else             { wt = WvT + (size_t)(y - 20) * 64 * D_; bias = bv + (y - 20) * 64; outp = vv; opitch = KVD_; col0 = (y - 20) * 64; mode = 2; }

  const int bm = blockIdx.x * 128;
  const int tid = threadIdx.x;
  const int w = tid >> 6, lane = tid & 63, quad = lane >> 4, l16 = lane & 15;
  const int lr = lane >> 3;          // staged sub-row 0..7
  const int gc = (lane & 7) ^ lr;    // swizzled source chunk
  const int sw = l16 & 7;            // frag-read swizzle selector

  const unsigned short* gA = xh + (size_t)(bm + w * 8 + lr) * D_ + gc * 8;
  const unsigned short* gB = wt + (size_t)(w * 8 + lr) * D_ + gc * 8;

  f32x4 acc[2][4];
#pragma unroll
  for (int i = 0; i < 2; ++i)
#pragma unroll
    for (int j = 0; j < 4; ++j) acc[i][j] = (f32x4){0.f, 0.f, 0.f, 0.f};

  // prologue: stage K-step 0 into buffer 0 (full drain here only)
#pragma unroll
  for (int rd = 0; rd < 4; ++rd)
    dma16(gA + (size_t)rd * 32 * D_, &As[0][rd * 2048 + w * 512]);
#pragma unroll
  for (int rd = 0; rd < 2; ++rd)
    dma16(gB + (size_t)rd * 32 * D_, &Bs[0][rd * 2048 + w * 512]);
  asm volatile("s_waitcnt vmcnt(0)" ::: "memory");
  __builtin_amdgcn_s_barrier();

  for (int ks = 0; ks < 16; ++ks) {
    const int cur = ks & 1;
    if (ks < 15) {
      const int k1 = (ks + 1) * 64;
#pragma unroll
      for (int rd = 0; rd < 4; ++rd)
        dma16(gA + (size_t)rd * 32 * D_ + k1, &As[cur ^ 1][rd * 2048 + w * 512]);
#pragma unroll
      for (int rd = 0; rd < 2; ++rd)
        dma16(gB + (size_t)rd * 32 * D_ + k1, &Bs[cur ^ 1][rd * 2048 + w * 512]);
      // wait for stage(ks) only; stage(ks+1)'s 6 DMAs stay in flight
      asm volatile("s_waitcnt vmcnt(6)" ::: "memory");
    } else {
      asm volatile("s_waitcnt vmcnt(0)" ::: "memory");
    }
    __builtin_amdgcn_s_barrier();

#pragma unroll
    for (int kk = 0; kk < 2; ++kk) {
      half8v fa[2], fb[4];
      const int slot = ((kk * 4 + quad) ^ sw) * 8;
#pragma unroll
      for (int mb = 0; mb < 2; ++mb)
        fa[mb] = *(const half8v*)&As[cur][(w * 32 + mb * 16 + l16) * 64 + slot];
#pragma unroll
      for (int nb = 0; nb < 4; ++nb)
        fb[nb] = *(const half8v*)&Bs[cur][(nb * 16 + l16) * 64 + slot];
#pragma unroll
      for (int mb = 0; mb < 2; ++mb)
#pragma unroll
        for (int nb = 0; nb < 4; ++nb)
          acc[mb][nb] = __builtin_amdgcn_mfma_f32_16x16x32_f16(fa[mb], fb[nb], acc[mb][nb], 0, 0, 0);
    }
    // WAR fence: all waves' ds_reads of buf cur retired (their consuming
    // MFMAs precede this point) before next step overwrites buf cur.
    __builtin_amdgcn_s_barrier();
  }

  float bsv[4];
#pragma unroll
  for (int nb = 0; nb < 4; ++nb) bsv[nb] = bias[nb * 16 + l16];

  if (mode == 2) {   // V: bias + cast only
#pragma unroll
    for (int mb = 0; mb < 2; ++mb)
#pragma unroll
      for (int nb = 0; nb < 4; ++nb)
#pragma unroll
        for (int r = 0; r < 4; ++r) {
          const int row = bm + w * 32 + mb * 16 + quad * 4 + r;
          outp[(size_t)row * opitch + col0 + nb * 16 + l16] = f2h(acc[mb][nb][r] + bsv[nb]);
        }
    return;
  }

  // Q/K: RMSNorm (+learned w) + factored 3D RoPE, fp32 pre-rounding.
  const float* nwp = (mode == 0) ? qn : kn;
  float wv[4];
#pragma unroll
  for (int nb = 0; nb < 4; ++nb) wv[nb] = nwp[nb * 16 + l16];
  const float f_th = __powf(THETA_, -(float)(l16 & 7) / 8.0f);   // t/h segs, dd=16
  const float f_w  = __powf(THETA_, -(float)l16 / 16.0f);        // w seg,  dd=32
  const float oscale = (mode == 0) ? 0.125f * LOG2E_ : 1.0f;     // attn scale * log2e
  const bool first8 = (l16 & 8) == 0;

  float snw[4], csw[4];
#pragma unroll
  for (int r = 0; r < 4; ++r)
    __sincosf((float)(quad * 4 + r) * f_w, &snw[r], &csw[r]);

#pragma unroll
  for (int mb = 0; mb < 2; ++mb) {
    const int nbase = (bm + w * 32 + mb * 16) & (N_ - 1);
    float snt, cst, snh, csh;
    __sincosf((float)(nbase >> 8) * f_th, &snt, &cst);
    __sincosf((float)((nbase >> 4) & 15) * f_th, &snh, &csh);
#pragma unroll
    for (int r = 0; r < 4; ++r) {
      float v[4];
      float ss = 0.f;
#pragma unroll
      for (int nb = 0; nb < 4; ++nb) { v[nb] = acc[mb][nb][r] + bsv[nb]; ss += v[nb] * v[nb]; }
      ss += __shfl_xor(ss, 1, 64);
      ss += __shfl_xor(ss, 2, 64);
      ss += __shfl_xor(ss, 4, 64);
      ss += __shfl_xor(ss, 8, 64);
      const float rs = rsqrtf(ss * (1.0f / 64.0f) + EPS_);
#pragma unroll
      for (int nb = 0; nb < 4; ++nb) v[nb] *= rs * wv[nb];

      const float p0 = __shfl_xor(v[0], 8, 64);
      const float p1 = __shfl_xor(v[1], 8, 64);
      const float o0 = v[0] * cst + (first8 ? -p0 : p0) * snt;
      const float o1 = v[1] * csh + (first8 ? -p1 : p1) * snh;
      const float o2 = v[2] * csw[r] - v[3] * snw[r];
      const float o3 = v[3] * csw[r] + v[2] * snw[r];

      const int row = bm + w * 32 + mb * 16 + quad * 4 + r;
      const size_t ob = (size_t)row * opitch + col0 + l16;
      outp[ob]      = f2h(o0 * oscale);
      outp[ob + 16] = f2h(o1 * oscale);
      outp[ob + 32] = f2h(o2 * oscale);
      outp[ob + 48] = f2h(o3 * oscale);
    }
  }
}

// ---------------------------------------------------------------------------
// Output projection: A = O (single f16), B = 64*Wo^T as f16 hi+lo (~22 bits).
// 128x64 tile (512 blocks), BK=64, 4 waves all-M. Same counted-vmcnt raw-
// barrier double-buffered schedule (8 dma16/thread/step -> vmcnt(8)).
// Epilogue multiplies by 1/64 (exact) and adds bias.
// ---------------------------------------------------------------------------
__global__ __launch_bounds__(256) void gemm_o(
    const unsigned short* __restrict__ ag,
    const unsigned short* __restrict__ WTh, const unsigned short* __restrict__ WTl,
    const float* __restrict__ bo, float* __restrict__ out)
{
  __shared__ unsigned short As[2][128 * 64];                 // 2x16 KB
  __shared__ unsigned short Bh[2][64 * 64], Bl[2][64 * 64];  // 2x8 KB each

  const int bm = blockIdx.x * 128, bn = blockIdx.y * 64;
  const int tid = threadIdx.x;
  const int w = tid >> 6, lane = tid & 63, quad = lane >> 4, l16 = lane & 15;
  const int lr = lane >> 3;
  const int gc = (lane & 7) ^ lr;
  const int sw = l16 & 7;

  const unsigned short* gA  = ag  + (size_t)(bm + w * 8 + lr) * D_ + gc * 8;
  const unsigned short* gBh = WTh + (size_t)(bn + w * 8 + lr) * D_ + gc * 8;
  const unsigned short* gBl = WTl + (size_t)(bn + w * 8 + lr) * D_ + gc * 8;

  f32x4 acc[2][4];
#pragma unroll
  for (int i = 0; i < 2; ++i)
#pragma unroll
    for (int j = 0; j < 4; ++j) acc[i][j] = (f32x4){0.f, 0.f, 0.f, 0.f};

  // prologue: stage K-step 0 into buffer 0 (full drain here only)
#pragma unroll
  for (int rd = 0; rd < 4; ++rd)
    dma16(gA + (size_t)rd * 32 * D_, &As[0][rd * 2048 + w * 512]);
#pragma unroll
  for (int rd = 0; rd < 2; ++rd) {
    dma16(gBh + (size_t)rd * 32 * D_, &Bh[0][rd * 2048 + w * 512]);
    dma16(gBl + (size_t)rd * 32 * D_, &Bl[0][rd * 2048 + w * 512]);
  }
  asm volatile("s_waitcnt vmcnt(0)" ::: "memory");
  __builtin_amdgcn_s_barrier();

  for (int ks = 0; ks < 16; ++ks) {
    const int cur = ks & 1;
    if (ks < 15) {
      const int k1 = (ks + 1) * 64;
#pragma unroll
      for (int rd = 0; rd < 4; ++rd)
        dma16(gA + (size_t)rd * 32 * D_ + k1, &As[cur ^ 1][rd * 2048 + w * 512]);
#pragma unroll
      for (int rd = 0; rd < 2; ++rd) {
        dma16(gBh + (size_t)rd * 32 * D_ + k1, &Bh[cur ^ 1][rd * 2048 + w * 512]);
        dma16(gBl + (size_t)rd * 32 * D_ + k1, &Bl[cur ^ 1][rd * 2048 + w * 512]);
      }
      asm volatile("s_waitcnt vmcnt(8)" ::: "memory");
    } else {
      asm volatile("s_waitcnt vmcnt(0)" ::: "memory");
    }
    __builtin_amdgcn_s_barrier();

#pragma unroll
    for (int kk = 0; kk < 2; ++kk) {
      half8v fa[2], fbh[4], fbl[4];
      const int slot = ((kk * 4 + quad) ^ sw) * 8;
#pragma unroll
      for (int mb = 0; mb < 2; ++mb)
        fa[mb] = *(const half8v*)&As[cur][(w * 32 + mb * 16 + l16) * 64 + slot];
#pragma unroll
      for (int nb = 0; nb < 4; ++nb) {
        const int ro = (nb * 16 + l16) * 64 + slot;
        fbh[nb] = *(const half8v*)&Bh[cur][ro];
        fbl[nb] = *(const half8v*)&Bl[cur][ro];
      }
#pragma unroll
      for (int mb = 0; mb < 2; ++mb)
#pragma unroll
        for (int nb = 0; nb < 4; ++nb) {
          acc[mb][nb] = __builtin_amdgcn_mfma_f32_16x16x32_f16(fa[mb], fbl[nb], acc[mb][nb], 0, 0, 0);
          acc[mb][nb] = __builtin_amdgcn_mfma_f32_16x16x32_f16(fa[mb], fbh[nb], acc[mb][nb], 0, 0, 0);
        }
    }
    __builtin_amdgcn_s_barrier();
  }

  float bsv[4];
#pragma unroll
  for (int nb = 0; nb < 4; ++nb) bsv[nb] = bo[bn + nb * 16 + l16];
#pragma unroll
  for (int mb = 0; mb < 2; ++mb)
#pragma unroll
    for (int nb = 0; nb < 4; ++nb)
#pragma unroll
      for (int r = 0; r < 4; ++r) {
        const int row = bm + w * 32 + mb * 16 + quad * 4 + r;
        const int col = bn + nb * 16 + l16;
        out[(size_t)row * D_ + col] = acc[mb][nb][r] * 0.015625f + bsv[nb];
      }
}

// ---------------------------------------------------------------------------
// MFMA flash attention — P-in-register, 8-wave / 256-row q-tile (round 5 form
// verbatim: best measured 46.7 us; the r8 KV-split regressed and is reverted).
// ---------------------------------------------------------------------------
__global__ __launch_bounds__(512, 2) void attn_mfma(
    const unsigned short* __restrict__ qg,
    const unsigned short* __restrict__ kg,
    const unsigned short* __restrict__ vg,
    unsigned short* __restrict__ og)
{
  __shared__ unsigned short Ks[2][128 * 64];   // swizzled, 2x16 KB
  __shared__ unsigned short Vt[2][64][136];    // [dim][key'], 2x17 KB

  const int bid = blockIdx.x;
  const int qt  = bid & 7;           // 8 q-tiles of 256 rows
  const int h   = (bid >> 3) & 15;
  const int b   = bid >> 7;
  const int kvh = h >> 2;            // GQA: q-head h -> kv-head h/4

  const int tid  = threadIdx.x;
  const int w    = tid >> 6;         // 0..7
  const int lane = tid & 63;
  const int quad = lane >> 4;
  const int l16  = lane & 15;
  const int lr = lane >> 3;
  const int gc = (lane & 7) ^ lr;
  const int sw = l16 & 7;

  // Q frags (B-operand: lane l16 = q-row, 8 dims at quad*8 / 32+quad*8).
  half8v aq[2][2];
#pragma unroll
  for (int qb = 0; qb < 2; ++qb) {
    const int qrow = qt * 256 + w * 32 + qb * 16 + l16;
    const unsigned short* qptr =
        qg + ((size_t)(b * N_ + qrow) * D_) + h * HD_ + quad * 8;
    aq[qb][0] = *(const half8v*)(qptr);
    aq[qb][1] = *(const half8v*)(qptr + 32);
  }

  // O^T accumulators: o_[qb][nb][r] = O[dim=nb*16+quad*4+r][qrow(l16)]
  f32x4 o_[2][4];
  float lrow[2] = {0.f, 0.f};        // per-lane softmax denom (q-row local)
#pragma unroll
  for (int qb = 0; qb < 2; ++qb)
#pragma unroll
    for (int i = 0; i < 4; ++i) o_[qb][i] = (f32x4){0.f, 0.f, 0.f, 0.f};

  // K DMA source: 2 dma16/wave x 8 waves cover 128 rows (row = rd*64 + w*8 + lr)
  const unsigned short* gK =
      kg + ((size_t)(b * N_) + w * 8 + lr) * KVD_ + kvh * HD_ + gc * 8;

  // V staging with the P-frag key' permutation:
  //   within-half key K (bits k5..k0) -> pos = k5*32 + (k3k2)*8 + k4*4 + k1k0
  // 512 threads: vhh = tid>>8 picks the 64-key half; thread loads key pair
  // (K0, K0+1), K0 = 2*vj + 32*vh, dims 8vs..8vs+7, packs one u32/dim at
  // column vhh*64 + pos(K0).
  const int vj  = tid & 15;
  const int vh  = (tid >> 4) & 1;
  const int vs  = (tid >> 5) & 7;
  const int vhh = tid >> 8;          // 0..1
  const int vcol = vhh * 64 + vh * 32 +
                   ((vj >> 1) & 3) * 8 + ((vj >> 3) & 1) * 4 + 2 * (vj & 1);
  const unsigned short* gV =
      vg + (size_t)(b * N_ + vhh * 64 + 2 * vj + 32 * vh) * KVD_ + kvh * HD_ + 8 * vs;

  // ---- prologue: stage tile 0, prefetch V tile 1 ----
#pragma unroll
  for (int rd = 0; rd < 2; ++rd)
    dma16(gK + (size_t)(rd * 64) * KVD_, &Ks[0][rd * 4096 + w * 512]);
  ushort8v va0 = *(const ushort8v*)(gV);
  ushort8v va1 = *(const ushort8v*)(gV + KVD_);
#pragma unroll
  for (int i = 0; i < 8; ++i)
    *(unsigned int*)&Vt[0][8 * vs + i][vcol] =
        (unsigned int)va0[i] | ((unsigned int)va1[i] << 16);
  {
    const unsigned short* p = gV + (size_t)128 * KVD_;
    va0 = *(const ushort8v*)(p);
    va1 = *(const ushort8v*)(p + KVD_);
  }
  __syncthreads();

  for (int kt = 0; kt < 16; ++kt) {
    const int cur = kt & 1;
    // stage tile kt+1 into the other buffer; DMA/ds_writes complete during
    // this tile's compute and are drained by the end-of-loop barrier.
    if (kt < 15) {
#pragma unroll
      for (int rd = 0; rd < 2; ++rd)
        dma16(gK + (size_t)((kt + 1) * 128 + rd * 64) * KVD_,
              &Ks[cur ^ 1][rd * 4096 + w * 512]);
#pragma unroll
      for (int i = 0; i < 8; ++i)
        *(unsigned int*)&Vt[cur ^ 1][8 * vs + i][vcol] =
            (unsigned int)va0[i] | ((unsigned int)va1[i] << 16);
      if (kt < 14) {
        const unsigned short* p = gV + (size_t)(kt + 2) * 128 * KVD_;
        va0 = *(const ushort8v*)(p);
        va1 = *(const ushort8v*)(p + KVD_);
      }
    }

    // ---- compute tile kt from Ks[cur], Vt[cur] ----
#pragma unroll
    for (int hh = 0; hh < 2; ++hh) {
      // S^T = K·Q^T : lane holds P[key=nb*16+quad*4+r][qrow=l16]
      f32x4 s[2][4];
#pragma unroll
      for (int nb = 0; nb < 4; ++nb) {
        const int kr = (hh * 64 + nb * 16 + l16) * 64;
        const half8v b0 = *(const half8v*)&Ks[cur][kr + (quad ^ sw) * 8];
        const half8v b1 = *(const half8v*)&Ks[cur][kr + ((4 + quad) ^ sw) * 8];
#pragma unroll
        for (int qb = 0; qb < 2; ++qb) {
          f32x4 z = (f32x4){0.f, 0.f, 0.f, 0.f};
          z = __builtin_amdgcn_mfma_f32_16x16x32_f16(b0, aq[qb][0], z, 0, 0, 0);
          s[qb][nb] = __builtin_amdgcn_mfma_f32_16x16x32_f16(b1, aq[qb][1], z, 0, 0, 0);
        }
      }

      // exp2 + pack to P-frags in registers (no LDS round-trip).
      // pf[qb][kc][j]: key K = (2kc+(j>>2))*16 + quad*4 + (j&3)
      half8v pf[2][2];
#pragma unroll
      for (int qb = 0; qb < 2; ++qb) {
        float ls = 0.f;
#pragma unroll
        for (int nb = 0; nb < 4; ++nb) {
          const float p0 = EXP2F(s[qb][nb][0]);
          const float p1 = EXP2F(s[qb][nb][1]);
          const float p2 = EXP2F(s[qb][nb][2]);
          const float p3 = EXP2F(s[qb][nb][3]);
          ls += (p0 + p1) + (p2 + p3);
          const int kc = nb >> 1, jo = (nb & 1) * 4;
          pf[qb][kc][jo + 0] = (_Float16)p0;
          pf[qb][kc][jo + 1] = (_Float16)p1;
          pf[qb][kc][jo + 2] = (_Float16)p2;
          pf[qb][kc][jo + 3] = (_Float16)p3;
        }
        lrow[qb] += ls;
      }

      // O^T += V^T · P^T ; V-frags shared across both q-subtiles
#pragma unroll
      for (int kc = 0; kc < 2; ++kc)
#pragma unroll
        for (int nb = 0; nb < 4; ++nb) {
          const half8v bv =
              *(const half8v*)&Vt[cur][nb * 16 + l16][hh * 64 + kc * 32 + quad * 8];
#pragma unroll
          for (int qb = 0; qb < 2; ++qb)
            o_[qb][nb] = __builtin_amdgcn_mfma_f32_16x16x32_f16(bv, pf[qb][kc], o_[qb][nb], 0, 0, 0);
        }
    }
    __syncthreads();
  }

  // epilogue: denom reduce across quads (same l16), write O^T as 8B chunks
#pragma unroll
  for (int qb = 0; qb < 2; ++qb) {
    float l = lrow[qb];
    l += __shfl_xor(l, 16, 64);
    l += __shfl_xor(l, 32, 64);
    const float inv = 1.0f / l;
    const int qrow = qt * 256 + w * 32 + qb * 16 + l16;
    const size_t base = (size_t)(b * N_ + qrow) * D_ + h * HD_;
#pragma unroll
    for (int nb = 0; nb < 4; ++nb) {
      half4v pk;
#pragma unroll
      for (int r = 0; r < 4; ++r) pk[r] = (_Float16)(o_[qb][nb][r] * inv);
      *(half4v*)&og[base + nb * 16 + quad * 4] = pk;
    }
  }
}

// ---------------------------------------------------------------------------
extern "C" void kernel_launch(void* const* d_in, const int* in_sizes, int n_in,
                              void* d_out, int out_size, void* d_ws, size_t ws_size,
                              hipStream_t stream) {
  const float* x  = (const float*)d_in[0];
  const float* Wq = (const float*)d_in[1];
  const float* bq = (const float*)d_in[2];
  const float* Wk = (const float*)d_in[3];
  const float* bk = (const float*)d_in[4];
  const float* Wv = (const float*)d_in[5];
  const float* bv = (const float*)d_in[6];
  const float* Wo = (const float*)d_in[7];
  const float* bo = (const float*)d_in[8];
  const float* qn = (const float*)d_in[9];
  const float* kn = (const float*)d_in[10];
  float* out = (float*)d_out;

  // Workspace (u16 units, ~27 MB):
  //  xh(4M) qv(4M) kv(1M) vv(1M) WqT(1M) WkT(.25M) WvT(.25M) WoTh(1M) WoTl(1M)
  //  attention output og aliases xh (dead after gemm_qkv).
  const size_t M4 = (size_t)BN_ * D_;
  const size_t M1 = (size_t)BN_ * KVD_;
  unsigned short* xh  = (unsigned short*)d_ws;
  unsigned short* qv  = xh + M4;
  unsigned short* kv  = qv + M4;
  unsigned short* vv  = kv + M1;
  unsigned short* WqT = vv + M1;
  unsigned short* WkT = WqT + (size_t)D_ * D_;
  unsigned short* WvT = WkT + (size_t)D_ * KVD_;
  unsigned short* WoTh = WvT + (size_t)D_ * KVD_;
  unsigned short* WoTl = WoTh + (size_t)D_ * D_;
  unsigned short* og  = xh;   // alias

  const dim3 blk(256);

  // 1) cast + all weight transposes in one launch
  prep<<<dim3(4608), blk, 0, stream>>>(x, Wq, Wk, Wv, Wo, xh, WqT, WkT, WvT, WoTh, WoTl);

  // 2) fused QKV projection + RMSNorm + RoPE (counted-vmcnt dbuf, 768 blocks)
  gemm_qkv<<<dim3(32, 24), blk, 0, stream>>>(xh, WqT, WkT, WvT, bq, bk, bv, qn, kn, qv, kv, vv);

  // 3) P-in-register MFMA flash attention (r5 form, 256 blocks x 512 thr)
  attn_mfma<<<dim3(B_ * NH_ * (N_ / 256)), dim3(512), 0, stream>>>(qv, kv, vv, og);

  // 4) output projection (counted-vmcnt dbuf, 512 blocks)
  gemm_o<<<dim3(32, 16), blk, 0, stream>>>(og, WoTh, WoTl, bo, out);
}

// Round 10
// 174.529 us; speedup vs baseline: 1.1036x; 1.0298x over previous
//
#include <hip/hip_runtime.h>
#include <hip/hip_bf16.h>
#include <math.h>

// Problem constants (fixed by the reference file)
constexpr int B_   = 2;
constexpr int N_   = 2048;   // T*HS*WS = 8*16*16
constexpr int D_   = 1024;
constexpr int NH_  = 16;
constexpr int NKV_ = 4;
constexpr int HD_  = 64;
constexpr int BN_  = 4096;   // B_*N_
constexpr int KVD_ = NKV_ * HD_;  // 256
constexpr float EPS_ = 1e-6f;
constexpr float THETA_ = 10000.0f;
constexpr float LOG2E_ = 1.4426950408889634f;

typedef _Float16 half8v __attribute__((ext_vector_type(8)));
typedef _Float16 half4v __attribute__((ext_vector_type(4)));
typedef unsigned short ushort8v __attribute__((ext_vector_type(8)));
typedef float f32x4 __attribute__((ext_vector_type(4)));

static __device__ __forceinline__ unsigned short f2h(float f) {
  union { _Float16 h; unsigned short u; } v; v.h = (_Float16)f; return v.u;
}
static __device__ __forceinline__ float h2f(unsigned short u) {
  union { unsigned short u; _Float16 h; } v; v.u = u; return (float)v.h;
}

// Hardware 2^x. q is pre-scaled by log2(e) so exp(s_raw) == exp2(s).
#if __has_builtin(__builtin_amdgcn_exp2f)
#define EXP2F(x) __builtin_amdgcn_exp2f(x)
#else
#define EXP2F(x) __expf((x) * 0.6931471805599453f)
#endif

// global -> LDS direct DMA, 16 B per lane. LDS dest = wave-uniform base +
// lane*16 (m104). The per-lane GLOBAL address is free, which lets us store an
// XOR-swizzled layout (chunk c of row r lands at slot c^(r&7)) so the b128
// fragment reads are conflict-free without padding.
static __device__ __forceinline__ void dma16(const unsigned short* g,
                                             unsigned short* l) {
  __builtin_amdgcn_global_load_lds(
      (const __attribute__((address_space(1))) unsigned int*)g,
      (__attribute__((address_space(3))) unsigned int*)l, 16, 0, 0);
}

// ---------------------------------------------------------------------------
// prep: one launch doing x->f16 cast + all 4 weight transposes (f16; Wo hi/lo
// with x64 pre-scale). Linear block-id partition.
// ---------------------------------------------------------------------------
static __device__ __forceinline__ void wtrans_tile(
    const float* __restrict__ W, int Nw, int K, float scale,
    unsigned short* __restrict__ WTh, unsigned short* __restrict__ WTl,
    int bx, int by, bool lo)
{
  __shared__ float tile[32][33];
  const int k0 = bx * 32, n0 = by * 32;
  const int c = threadIdx.x & 31, rb = threadIdx.x >> 5;
#pragma unroll
  for (int i = 0; i < 4; ++i) {
    const int r = rb + i * 8;
    tile[r][c] = W[(size_t)(k0 + r) * Nw + n0 + c];
  }
  __syncthreads();
#pragma unroll
  for (int i = 0; i < 4; ++i) {
    const int r = rb + i * 8;
    const float v = tile[c][r] * scale;   // = W[k0+c][n0+r] * scale
    const size_t o = (size_t)(n0 + r) * K + k0 + c;
    const unsigned short hi = f2h(v);
    WTh[o] = hi;
    if (lo) WTl[o] = f2h(v - h2f(hi));
  }
}

__global__ __launch_bounds__(256) void prep(
    const float* __restrict__ x,
    const float* __restrict__ Wq, const float* __restrict__ Wk,
    const float* __restrict__ Wv, const float* __restrict__ Wo,
    unsigned short* __restrict__ xh,
    unsigned short* __restrict__ WqT, unsigned short* __restrict__ WkT,
    unsigned short* __restrict__ WvT,
    unsigned short* __restrict__ WoTh, unsigned short* __restrict__ WoTl)
{
  const int bid = blockIdx.x;
  if (bid < 2048) {
    const int i = (bid * 256 + threadIdx.x) * 8;
    const float4 v0 = *(const float4*)(x + i);
    const float4 v1 = *(const float4*)(x + i + 4);
    ushort8v o;
    o[0] = f2h(v0.x); o[1] = f2h(v0.y); o[2] = f2h(v0.z); o[3] = f2h(v0.w);
    o[4] = f2h(v1.x); o[5] = f2h(v1.y); o[6] = f2h(v1.z); o[7] = f2h(v1.w);
    *(ushort8v*)(xh + i) = o;
  } else if (bid < 3072) {
    const int l = bid - 2048;
    wtrans_tile(Wq, D_, D_, 1.0f, WqT, nullptr, l & 31, l >> 5, false);
  } else if (bid < 3328) {
    const int l = bid - 3072;
    wtrans_tile(Wk, KVD_, D_, 1.0f, WkT, nullptr, l & 31, l >> 5, false);
  } else if (bid < 3584) {
    const int l = bid - 3328;
    wtrans_tile(Wv, KVD_, D_, 1.0f, WvT, nullptr, l & 31, l >> 5, false);
  } else {
    const int l = bid - 3584;
    wtrans_tile(Wo, D_, D_, 64.0f, WoTh, WoTl, l & 31, l >> 5, true);
  }
}

// ---------------------------------------------------------------------------
// Fused QKV projection + RMSNorm + 3D RoPE in the epilogue (r5 body).
// 128x64 tile, BK=64, 4 waves all-M, m97-style DMA staging.
// NEW: flat grid 768 + XCD-locality decode (T1): xcd = bid%8 owns M-slab
// bx in [xcd*4, xcd*4+4) for ALL 24 y-columns. Per-XCD working set =
// A-slab 1 MB + B 3 MB = exact 4 MB L2 fit; cross-chip A re-fetch drops
// 192 MB -> 8 MB (A was previously re-read by every y-column through L3).
// Q output carries log2(e) so attention can use hw exp2.
// ---------------------------------------------------------------------------
__global__ __launch_bounds__(256) void gemm_qkv(
    const unsigned short* __restrict__ xh,
    const unsigned short* __restrict__ WqT, const unsigned short* __restrict__ WkT,
    const unsigned short* __restrict__ WvT,
    const float* __restrict__ bq, const float* __restrict__ bk, const float* __restrict__ bv,
    const float* __restrict__ qn, const float* __restrict__ kn,
    unsigned short* __restrict__ qv, unsigned short* __restrict__ kv,
    unsigned short* __restrict__ vv)
{
  __shared__ unsigned short As[128 * 64];   // swizzled, 16 KB
  __shared__ unsigned short Bs[64 * 64];    // swizzled, 8 KB

  // XCD-locality decode: bid = g*8 + xcd; bx = xcd*4 + (g&3); y = g>>2.
  // Bijective (768 % 8 == 0). Same-y blocks within an XCD are consecutive.
  const int bid = blockIdx.x;
  const int xcd = bid & 7;
  const int g   = bid >> 3;            // 0..95
  const int bx  = xcd * 4 + (g & 3);   // 0..31 M-tile
  const int y   = g >> 2;              // 0..23

  const unsigned short* wt; const float* bias; unsigned short* outp; int opitch, col0, mode;
  if (y < 16)      { wt = WqT + (size_t)y * 64 * D_;        bias = bq + y * 64;        outp = qv; opitch = D_;   col0 = y * 64;        mode = 0; }
  else if (y < 20) { wt = WkT + (size_t)(y - 16) * 64 * D_; bias = bk + (y - 16) * 64; outp = kv; opitch = KVD_; col0 = (y - 16) * 64; mode = 1; }
  else             { wt = WvT + (size_t)(y - 20) * 64 * D_; bias = bv + (y - 20) * 64; outp = vv; opitch = KVD_; col0 = (y - 20) * 64; mode = 2; }

  const int bm = bx * 128;
  const int tid = threadIdx.x;
  const int w = tid >> 6, lane = tid & 63, quad = lane >> 4, l16 = lane & 15;
  const int lr = lane >> 3;          // staged sub-row 0..7
  const int gc = (lane & 7) ^ lr;    // swizzled source chunk
  const int sw = l16 & 7;            // frag-read swizzle selector

  const unsigned short* gA = xh + (size_t)(bm + w * 8 + lr) * D_ + gc * 8;
  const unsigned short* gB = wt + (size_t)(w * 8 + lr) * D_ + gc * 8;

  f32x4 acc[2][4];
#pragma unroll
  for (int i = 0; i < 2; ++i)
#pragma unroll
    for (int j = 0; j < 4; ++j) acc[i][j] = (f32x4){0.f, 0.f, 0.f, 0.f};

  for (int k0 = 0; k0 < D_; k0 += 64) {
    __syncthreads();
#pragma unroll
    for (int rd = 0; rd < 4; ++rd)
      dma16(gA + (size_t)rd * 32 * D_ + k0, &As[rd * 2048 + w * 512]);
#pragma unroll
    for (int rd = 0; rd < 2; ++rd)
      dma16(gB + (size_t)rd * 32 * D_ + k0, &Bs[rd * 2048 + w * 512]);
    __syncthreads();

#pragma unroll
    for (int kk = 0; kk < 2; ++kk) {
      half8v fa[2], fb[4];
#pragma unroll
      for (int mb = 0; mb < 2; ++mb)
        fa[mb] = *(const half8v*)&As[(w * 32 + mb * 16 + l16) * 64 + ((kk * 4 + quad) ^ sw) * 8];
#pragma unroll
      for (int nb = 0; nb < 4; ++nb)
        fb[nb] = *(const half8v*)&Bs[(nb * 16 + l16) * 64 + ((kk * 4 + quad) ^ sw) * 8];
#pragma unroll
      for (int mb = 0; mb < 2; ++mb)
#pragma unroll
        for (int nb = 0; nb < 4; ++nb)
          acc[mb][nb] = __builtin_amdgcn_mfma_f32_16x16x32_f16(fa[mb], fb[nb], acc[mb][nb], 0, 0, 0);
    }
  }

  float bsv[4];
#pragma unroll
  for (int nb = 0; nb < 4; ++nb) bsv[nb] = bias[nb * 16 + l16];

  if (mode == 2) {   // V: bias + cast only
#pragma unroll
    for (int mb = 0; mb < 2; ++mb)
#pragma unroll
      for (int nb = 0; nb < 4; ++nb)
#pragma unroll
        for (int r = 0; r < 4; ++r) {
          const int row = bm + w * 32 + mb * 16 + quad * 4 + r;
          outp[(size_t)row * opitch + col0 + nb * 16 + l16] = f2h(acc[mb][nb][r] + bsv[nb]);
        }
    return;
  }

  // Q/K: RMSNorm (+learned w) + factored 3D RoPE, fp32 pre-rounding.
  const float* nwp = (mode == 0) ? qn : kn;
  float wv[4];
#pragma unroll
  for (int nb = 0; nb < 4; ++nb) wv[nb] = nwp[nb * 16 + l16];
  const float f_th = __powf(THETA_, -(float)(l16 & 7) / 8.0f);   // t/h segs, dd=16
  const float f_w  = __powf(THETA_, -(float)l16 / 16.0f);        // w seg,  dd=32
  const float oscale = (mode == 0) ? 0.125f * LOG2E_ : 1.0f;     // attn scale * log2e
  const bool first8 = (l16 & 8) == 0;

  float snw[4], csw[4];
#pragma unroll
  for (int r = 0; r < 4; ++r)
    __sincosf((float)(quad * 4 + r) * f_w, &snw[r], &csw[r]);

#pragma unroll
  for (int mb = 0; mb < 2; ++mb) {
    const int nbase = (bm + w * 32 + mb * 16) & (N_ - 1);
    float snt, cst, snh, csh;
    __sincosf((float)(nbase >> 8) * f_th, &snt, &cst);
    __sincosf((float)((nbase >> 4) & 15) * f_th, &snh, &csh);
#pragma unroll
    for (int r = 0; r < 4; ++r) {
      float v[4];
      float ss = 0.f;
#pragma unroll
      for (int nb = 0; nb < 4; ++nb) { v[nb] = acc[mb][nb][r] + bsv[nb]; ss += v[nb] * v[nb]; }
      ss += __shfl_xor(ss, 1, 64);
      ss += __shfl_xor(ss, 2, 64);
      ss += __shfl_xor(ss, 4, 64);
      ss += __shfl_xor(ss, 8, 64);
      const float rs = rsqrtf(ss * (1.0f / 64.0f) + EPS_);
#pragma unroll
      for (int nb = 0; nb < 4; ++nb) v[nb] *= rs * wv[nb];

      const float p0 = __shfl_xor(v[0], 8, 64);
      const float p1 = __shfl_xor(v[1], 8, 64);
      const float o0 = v[0] * cst + (first8 ? -p0 : p0) * snt;
      const float o1 = v[1] * csh + (first8 ? -p1 : p1) * snh;
      const float o2 = v[2] * csw[r] - v[3] * snw[r];
      const float o3 = v[3] * csw[r] + v[2] * snw[r];

      const int row = bm + w * 32 + mb * 16 + quad * 4 + r;
      const size_t ob = (size_t)row * opitch + col0 + l16;
      outp[ob]      = f2h(o0 * oscale);
      outp[ob + 16] = f2h(o1 * oscale);
      outp[ob + 32] = f2h(o2 * oscale);
      outp[ob + 48] = f2h(o3 * oscale);
    }
  }
}

// ---------------------------------------------------------------------------
// Output projection (r5 body): A = O (single f16), B = 64*Wo^T f16 hi+lo.
// 128x64 tile, BK=64, 4 waves all-M. NEW: flat grid 512 + XCD decode: each
// XCD owns M-slab bx in [xcd*4, xcd*4+4) for all 16 y (A-slab 1 MB resident;
// B panels shared by the 4 consecutive same-y blocks). A re-fetch 128->8 MB.
// ---------------------------------------------------------------------------
__global__ __launch_bounds__(256) void gemm_o(
    const unsigned short* __restrict__ ag,
    const unsigned short* __restrict__ WTh, const unsigned short* __restrict__ WTl,
    const float* __restrict__ bo, float* __restrict__ out)
{
  __shared__ unsigned short As[128 * 64];
  __shared__ unsigned short Bh[64 * 64], Bl[64 * 64];

  const int bid = blockIdx.x;
  const int xcd = bid & 7;
  const int g   = bid >> 3;            // 0..63
  const int bx  = xcd * 4 + (g & 3);   // 0..31
  const int by  = g >> 2;              // 0..15

  const int bm = bx * 128, bn = by * 64;
  const int tid = threadIdx.x;
  const int w = tid >> 6, lane = tid & 63, quad = lane >> 4, l16 = lane & 15;
  const int lr = lane >> 3;
  const int gc = (lane & 7) ^ lr;
  const int sw = l16 & 7;

  const unsigned short* gA  = ag  + (size_t)(bm + w * 8 + lr) * D_ + gc * 8;
  const unsigned short* gBh = WTh + (size_t)(bn + w * 8 + lr) * D_ + gc * 8;
  const unsigned short* gBl = WTl + (size_t)(bn + w * 8 + lr) * D_ + gc * 8;

  f32x4 acc[2][4];
#pragma unroll
  for (int i = 0; i < 2; ++i)
#pragma unroll
    for (int j = 0; j < 4; ++j) acc[i][j] = (f32x4){0.f, 0.f, 0.f, 0.f};

  for (int k0 = 0; k0 < D_; k0 += 64) {
    __syncthreads();
#pragma unroll
    for (int rd = 0; rd < 4; ++rd)
      dma16(gA + (size_t)rd * 32 * D_ + k0, &As[rd * 2048 + w * 512]);
#pragma unroll
    for (int rd = 0; rd < 2; ++rd) {
      dma16(gBh + (size_t)rd * 32 * D_ + k0, &Bh[rd * 2048 + w * 512]);
      dma16(gBl + (size_t)rd * 32 * D_ + k0, &Bl[rd * 2048 + w * 512]);
    }
    __syncthreads();

#pragma unroll
    for (int kk = 0; kk < 2; ++kk) {
      half8v fa[2], fbh[4], fbl[4];
#pragma unroll
      for (int mb = 0; mb < 2; ++mb)
        fa[mb] = *(const half8v*)&As[(w * 32 + mb * 16 + l16) * 64 + ((kk * 4 + quad) ^ sw) * 8];
#pragma unroll
      for (int nb = 0; nb < 4; ++nb) {
        const int ro = (nb * 16 + l16) * 64 + ((kk * 4 + quad) ^ sw) * 8;
        fbh[nb] = *(const half8v*)&Bh[ro];
        fbl[nb] = *(const half8v*)&Bl[ro];
      }
#pragma unroll
      for (int mb = 0; mb < 2; ++mb)
#pragma unroll
        for (int nb = 0; nb < 4; ++nb) {
          acc[mb][nb] = __builtin_amdgcn_mfma_f32_16x16x32_f16(fa[mb], fbl[nb], acc[mb][nb], 0, 0, 0);
          acc[mb][nb] = __builtin_amdgcn_mfma_f32_16x16x32_f16(fa[mb], fbh[nb], acc[mb][nb], 0, 0, 0);
        }
    }
  }

  float bsv[4];
#pragma unroll
  for (int nb = 0; nb < 4; ++nb) bsv[nb] = bo[bn + nb * 16 + l16];
#pragma unroll
  for (int mb = 0; mb < 2; ++mb)
#pragma unroll
    for (int nb = 0; nb < 4; ++nb)
#pragma unroll
      for (int r = 0; r < 4; ++r) {
        const int row = bm + w * 32 + mb * 16 + quad * 4 + r;
        const int col = bn + nb * 16 + l16;
        out[(size_t)row * D_ + col] = acc[mb][nb][r] * 0.015625f + bsv[nb];
      }
}

// ---------------------------------------------------------------------------
// MFMA flash attention — P-in-register, 8-wave / 256-row q-tile (r5 body).
// NEW: XCD-locality decode: xcd = b*4 + kvh, so all 32 blocks sharing one
// (b,kvh) K/V slice (0.5 MB) live on one XCD; with their 4 Q-slices (1 MB)
// the per-XCD working set is L2-resident. K/V L3 re-read 128 MB -> 4 MB.
// ---------------------------------------------------------------------------
__global__ __launch_bounds__(512, 2) void attn_mfma(
    const unsigned short* __restrict__ qg,
    const unsigned short* __restrict__ kg,
    const unsigned short* __restrict__ vg,
    unsigned short* __restrict__ og)
{
  __shared__ unsigned short Ks[2][128 * 64];   // swizzled, 2x16 KB
  __shared__ unsigned short Vt[2][64][136];    // [dim][key'], 2x17 KB

  // decode: bid = g*8 + xcd; xcd = b*4 + kvh; g = qt*4 + hsub (bijective, 256)
  const int bid = blockIdx.x;
  const int xcd = bid & 7;
  const int g   = bid >> 3;          // 0..31
  const int b   = xcd >> 2;
  const int kvh = xcd & 3;
  const int h   = kvh * 4 + (g & 3);
  const int qt  = g >> 2;            // 0..7

  const int tid  = threadIdx.x;
  const int w    = tid >> 6;         // 0..7
  const int lane = tid & 63;
  const int quad = lane >> 4;
  const int l16  = lane & 15;
  const int lr = lane >> 3;
  const int gc = (lane & 7) ^ lr;
  const int sw = l16 & 7;

  // Q frags (B-operand: lane l16 = q-row, 8 dims at quad*8 / 32+quad*8).
  half8v aq[2][2];
#pragma unroll
  for (int qb = 0; qb < 2; ++qb) {
    const int qrow = qt * 256 + w * 32 + qb * 16 + l16;
    const unsigned short* qptr =
        qg + ((size_t)(b * N_ + qrow) * D_) + h * HD_ + quad * 8;
    aq[qb][0] = *(const half8v*)(qptr);
    aq[qb][1] = *(const half8v*)(qptr + 32);
  }

  // O^T accumulators: o_[qb][nb][r] = O[dim=nb*16+quad*4+r][qrow(l16)]
  f32x4 o_[2][4];
  float lrow[2] = {0.f, 0.f};        // per-lane softmax denom (q-row local)
#pragma unroll
  for (int qb = 0; qb < 2; ++qb)
#pragma unroll
    for (int i = 0; i < 4; ++i) o_[qb][i] = (f32x4){0.f, 0.f, 0.f, 0.f};

  // K DMA source: 2 dma16/wave x 8 waves cover 128 rows (row = rd*64 + w*8 + lr)
  const unsigned short* gK =
      kg + ((size_t)(b * N_) + w * 8 + lr) * KVD_ + kvh * HD_ + gc * 8;

  // V staging with the P-frag key' permutation:
  //   within-half key K (bits k5..k0) -> pos = k5*32 + (k3k2)*8 + k4*4 + k1k0
  // 512 threads: vhh = tid>>8 picks the 64-key half; thread loads key pair
  // (K0, K0+1), K0 = 2*vj + 32*vh, dims 8vs..8vs+7, packs one u32/dim at
  // column vhh*64 + pos(K0).
  const int vj  = tid & 15;
  const int vh  = (tid >> 4) & 1;
  const int vs  = (tid >> 5) & 7;
  const int vhh = tid >> 8;          // 0..1
  const int vcol = vhh * 64 + vh * 32 +
                   ((vj >> 1) & 3) * 8 + ((vj >> 3) & 1) * 4 + 2 * (vj & 1);
  const unsigned short* gV =
      vg + (size_t)(b * N_ + vhh * 64 + 2 * vj + 32 * vh) * KVD_ + kvh * HD_ + 8 * vs;

  // ---- prologue: stage tile 0, prefetch V tile 1 ----
#pragma unroll
  for (int rd = 0; rd < 2; ++rd)
    dma16(gK + (size_t)(rd * 64) * KVD_, &Ks[0][rd * 4096 + w * 512]);
  ushort8v va0 = *(const ushort8v*)(gV);
  ushort8v va1 = *(const ushort8v*)(gV + KVD_);
#pragma unroll
  for (int i = 0; i < 8; ++i)
    *(unsigned int*)&Vt[0][8 * vs + i][vcol] =
        (unsigned int)va0[i] | ((unsigned int)va1[i] << 16);
  {
    const unsigned short* p = gV + (size_t)128 * KVD_;
    va0 = *(const ushort8v*)(p);
    va1 = *(const ushort8v*)(p + KVD_);
  }
  __syncthreads();

  for (int kt = 0; kt < 16; ++kt) {
    const int cur = kt & 1;
    // stage tile kt+1 into the other buffer; DMA/ds_writes complete during
    // this tile's compute and are drained by the end-of-loop barrier.
    if (kt < 15) {
#pragma unroll
      for (int rd = 0; rd < 2; ++rd)
        dma16(gK + (size_t)((kt + 1) * 128 + rd * 64) * KVD_,
              &Ks[cur ^ 1][rd * 4096 + w * 512]);
#pragma unroll
      for (int i = 0; i < 8; ++i)
        *(unsigned int*)&Vt[cur ^ 1][8 * vs + i][vcol] =
            (unsigned int)va0[i] | ((unsigned int)va1[i] << 16);
      if (kt < 14) {
        const unsigned short* p = gV + (size_t)(kt + 2) * 128 * KVD_;
        va0 = *(const ushort8v*)(p);
        va1 = *(const ushort8v*)(p + KVD_);
      }
    }

    // ---- compute tile kt from Ks[cur], Vt[cur] ----
#pragma unroll
    for (int hh = 0; hh < 2; ++hh) {
      // S^T = K·Q^T : lane holds P[key=nb*16+quad*4+r][qrow=l16]
      f32x4 s[2][4];
#pragma unroll
      for (int nb = 0; nb < 4; ++nb) {
        const int kr = (hh * 64 + nb * 16 + l16) * 64;
        const half8v b0 = *(const half8v*)&Ks[cur][kr + (quad ^ sw) * 8];
        const half8v b1 = *(const half8v*)&Ks[cur][kr + ((4 + quad) ^ sw) * 8];
#pragma unroll
        for (int qb = 0; qb < 2; ++qb) {
          f32x4 z = (f32x4){0.f, 0.f, 0.f, 0.f};
          z = __builtin_amdgcn_mfma_f32_16x16x32_f16(b0, aq[qb][0], z, 0, 0, 0);
          s[qb][nb] = __builtin_amdgcn_mfma_f32_16x16x32_f16(b1, aq[qb][1], z, 0, 0, 0);
        }
      }

      // exp2 + pack to P-frags in registers (no LDS round-trip).
      // pf[qb][kc][j]: key K = (2kc+(j>>2))*16 + quad*4 + (j&3)
      half8v pf[2][2];
#pragma unroll
      for (int qb = 0; qb < 2; ++qb) {
        float ls = 0.f;
#pragma unroll
        for (int nb = 0; nb < 4; ++nb) {
          const float p0 = EXP2F(s[qb][nb][0]);
          const float p1 = EXP2F(s[qb][nb][1]);
          const float p2 = EXP2F(s[qb][nb][2]);
          const float p3 = EXP2F(s[qb][nb][3]);
          ls += (p0 + p1) + (p2 + p3);
          const int kc = nb >> 1, jo = (nb & 1) * 4;
          pf[qb][kc][jo + 0] = (_Float16)p0;
          pf[qb][kc][jo + 1] = (_Float16)p1;
          pf[qb][kc][jo + 2] = (_Float16)p2;
          pf[qb][kc][jo + 3] = (_Float16)p3;
        }
        lrow[qb] += ls;
      }

      // O^T += V^T · P^T ; V-frags shared across both q-subtiles
#pragma unroll
      for (int kc = 0; kc < 2; ++kc)
#pragma unroll
        for (int nb = 0; nb < 4; ++nb) {
          const half8v bv =
              *(const half8v*)&Vt[cur][nb * 16 + l16][hh * 64 + kc * 32 + quad * 8];
#pragma unroll
          for (int qb = 0; qb < 2; ++qb)
            o_[qb][nb] = __builtin_amdgcn_mfma_f32_16x16x32_f16(bv, pf[qb][kc], o_[qb][nb], 0, 0, 0);
        }
    }
    __syncthreads();
  }

  // epilogue: denom reduce across quads (same l16), write O^T as 8B chunks
#pragma unroll
  for (int qb = 0; qb < 2; ++qb) {
    float l = lrow[qb];
    l += __shfl_xor(l, 16, 64);
    l += __shfl_xor(l, 32, 64);
    const float inv = 1.0f / l;
    const int qrow = qt * 256 + w * 32 + qb * 16 + l16;
    const size_t base = (size_t)(b * N_ + qrow) * D_ + h * HD_;
#pragma unroll
    for (int nb = 0; nb < 4; ++nb) {
      half4v pk;
#pragma unroll
      for (int r = 0; r < 4; ++r) pk[r] = (_Float16)(o_[qb][nb][r] * inv);
      *(half4v*)&og[base + nb * 16 + quad * 4] = pk;
    }
  }
}

// ---------------------------------------------------------------------------
extern "C" void kernel_launch(void* const* d_in, const int* in_sizes, int n_in,
                              void* d_out, int out_size, void* d_ws, size_t ws_size,
                              hipStream_t stream) {
  const float* x  = (const float*)d_in[0];
  const float* Wq = (const float*)d_in[1];
  const float* bq = (const float*)d_in[2];
  const float* Wk = (const float*)d_in[3];
  const float* bk = (const float*)d_in[4];
  const float* Wv = (const float*)d_in[5];
  const float* bv = (const float*)d_in[6];
  const float* Wo = (const float*)d_in[7];
  const float* bo = (const float*)d_in[8];
  const float* qn = (const float*)d_in[9];
  const float* kn = (const float*)d_in[10];
  float* out = (float*)d_out;

  // Workspace (u16 units, ~27 MB):
  //  xh(4M) qv(4M) kv(1M) vv(1M) WqT(1M) WkT(.25M) WvT(.25M) WoTh(1M) WoTl(1M)
  //  attention output og aliases xh (dead after gemm_qkv).
  const size_t M4 = (size_t)BN_ * D_;
  const size_t M1 = (size_t)BN_ * KVD_;
  unsigned short* xh  = (unsigned short*)d_ws;
  unsigned short* qv  = xh + M4;
  unsigned short* kv  = qv + M4;
  unsigned short* vv  = kv + M1;
  unsigned short* WqT = vv + M1;
  unsigned short* WkT = WqT + (size_t)D_ * D_;
  unsigned short* WvT = WkT + (size_t)D_ * KVD_;
  unsigned short* WoTh = WvT + (size_t)D_ * KVD_;
  unsigned short* WoTl = WoTh + (size_t)D_ * D_;
  unsigned short* og  = xh;   // alias

  const dim3 blk(256);

  // 1) cast + all weight transposes in one launch
  prep<<<dim3(4608), blk, 0, stream>>>(x, Wq, Wk, Wv, Wo, xh, WqT, WkT, WvT, WoTh, WoTl);

  // 2) fused QKV projection + RMSNorm + RoPE (XCD-swizzled flat grid 768)
  gemm_qkv<<<dim3(768), blk, 0, stream>>>(xh, WqT, WkT, WvT, bq, bk, bv, qn, kn, qv, kv, vv);

  // 3) P-in-register MFMA flash attention (XCD-swizzled, 256 blocks x 512 thr)
  attn_mfma<<<dim3(256), dim3(512), 0, stream>>>(qv, kv, vv, og);

  // 4) output projection (XCD-swizzled flat grid 512)
  gemm_o<<<dim3(512), blk, 0, stream>>>(og, WoTh, WoTl, bo, out);
}

// Round 11
// 173.785 us; speedup vs baseline: 1.1084x; 1.0043x over previous
//
#include <hip/hip_runtime.h>
#include <hip/hip_bf16.h>
#include <math.h>

// Problem constants (fixed by the reference file)
constexpr int B_   = 2;
constexpr int N_   = 2048;   // T*HS*WS = 8*16*16
constexpr int D_   = 1024;
constexpr int NH_  = 16;
constexpr int NKV_ = 4;
constexpr int HD_  = 64;
constexpr int BN_  = 4096;   // B_*N_
constexpr int KVD_ = NKV_ * HD_;  // 256
constexpr float EPS_ = 1e-6f;
constexpr float THETA_ = 10000.0f;
constexpr float LOG2E_ = 1.4426950408889634f;

typedef _Float16 half8v __attribute__((ext_vector_type(8)));
typedef _Float16 half4v __attribute__((ext_vector_type(4)));
typedef unsigned short ushort8v __attribute__((ext_vector_type(8)));
typedef float f32x4 __attribute__((ext_vector_type(4)));

static __device__ __forceinline__ unsigned short f2h(float f) {
  union { _Float16 h; unsigned short u; } v; v.h = (_Float16)f; return v.u;
}
static __device__ __forceinline__ float h2f(unsigned short u) {
  union { unsigned short u; _Float16 h; } v; v.u = u; return (float)v.h;
}

// Hardware 2^x. q is pre-scaled by log2(e) so exp(s_raw) == exp2(s).
#if __has_builtin(__builtin_amdgcn_exp2f)
#define EXP2F(x) __builtin_amdgcn_exp2f(x)
#else
#define EXP2F(x) __expf((x) * 0.6931471805599453f)
#endif

// global -> LDS direct DMA, 16 B per lane. LDS dest = wave-uniform base +
// lane*16 (m104). The per-lane GLOBAL address is free, which lets us store an
// XOR-swizzled layout (chunk c of row r lands at slot c^(r&7)) so the b128
// fragment reads are conflict-free without padding.
static __device__ __forceinline__ void dma16(const unsigned short* g,
                                             unsigned short* l) {
  __builtin_amdgcn_global_load_lds(
      (const __attribute__((address_space(1))) unsigned int*)g,
      (__attribute__((address_space(3))) unsigned int*)l, 16, 0, 0);
}

// ---------------------------------------------------------------------------
// prep: one launch doing x->f16 cast + all 4 weight transposes (f16; Wo hi/lo
// with x64 pre-scale). Linear block-id partition.
// ---------------------------------------------------------------------------
static __device__ __forceinline__ void wtrans_tile(
    const float* __restrict__ W, int Nw, int K, float scale,
    unsigned short* __restrict__ WTh, unsigned short* __restrict__ WTl,
    int bx, int by, bool lo)
{
  __shared__ float tile[32][33];
  const int k0 = bx * 32, n0 = by * 32;
  const int c = threadIdx.x & 31, rb = threadIdx.x >> 5;
#pragma unroll
  for (int i = 0; i < 4; ++i) {
    const int r = rb + i * 8;
    tile[r][c] = W[(size_t)(k0 + r) * Nw + n0 + c];
  }
  __syncthreads();
#pragma unroll
  for (int i = 0; i < 4; ++i) {
    const int r = rb + i * 8;
    const float v = tile[c][r] * scale;   // = W[k0+c][n0+r] * scale
    const size_t o = (size_t)(n0 + r) * K + k0 + c;
    const unsigned short hi = f2h(v);
    WTh[o] = hi;
    if (lo) WTl[o] = f2h(v - h2f(hi));
  }
}

__global__ __launch_bounds__(256) void prep(
    const float* __restrict__ x,
    const float* __restrict__ Wq, const float* __restrict__ Wk,
    const float* __restrict__ Wv, const float* __restrict__ Wo,
    unsigned short* __restrict__ xh,
    unsigned short* __restrict__ WqT, unsigned short* __restrict__ WkT,
    unsigned short* __restrict__ WvT,
    unsigned short* __restrict__ WoTh, unsigned short* __restrict__ WoTl)
{
  const int bid = blockIdx.x;
  if (bid < 2048) {
    const int i = (bid * 256 + threadIdx.x) * 8;
    const float4 v0 = *(const float4*)(x + i);
    const float4 v1 = *(const float4*)(x + i + 4);
    ushort8v o;
    o[0] = f2h(v0.x); o[1] = f2h(v0.y); o[2] = f2h(v0.z); o[3] = f2h(v0.w);
    o[4] = f2h(v1.x); o[5] = f2h(v1.y); o[6] = f2h(v1.z); o[7] = f2h(v1.w);
    *(ushort8v*)(xh + i) = o;
  } else if (bid < 3072) {
    const int l = bid - 2048;
    wtrans_tile(Wq, D_, D_, 1.0f, WqT, nullptr, l & 31, l >> 5, false);
  } else if (bid < 3328) {
    const int l = bid - 3072;
    wtrans_tile(Wk, KVD_, D_, 1.0f, WkT, nullptr, l & 31, l >> 5, false);
  } else if (bid < 3584) {
    const int l = bid - 3328;
    wtrans_tile(Wv, KVD_, D_, 1.0f, WvT, nullptr, l & 31, l >> 5, false);
  } else {
    const int l = bid - 3584;
    wtrans_tile(Wo, D_, D_, 64.0f, WoTh, WoTl, l & 31, l >> 5, true);
  }
}

// ---------------------------------------------------------------------------
// Fused QKV projection + RMSNorm + 3D RoPE in the epilogue.
// 128x64 tile, 4 waves all-M, m97-style DMA staging, XCD-locality decode.
// NEW (r11): BK=128 via PANEL PAIRING — the K-tile is two 64-col panels,
// each staged/read with the unchanged 64-col dma/swizzle/fragment math
// (panel = kk>>1, within-panel chunk (kk&1)*4+quad). K-loop 16 -> 8 steps:
// half the {issue -> vmcnt-drain -> barrier} fixed costs, same DMA/MFMA
// totals. LDS 24 -> 48 KB, still 3 blocks/CU (the m132 occupancy trap
// avoided). Q output carries log2(e) so attention can use hw exp2.
// ---------------------------------------------------------------------------
__global__ __launch_bounds__(256) void gemm_qkv(
    const unsigned short* __restrict__ xh,
    const unsigned short* __restrict__ WqT, const unsigned short* __restrict__ WkT,
    const unsigned short* __restrict__ WvT,
    const float* __restrict__ bq, const float* __restrict__ bk, const float* __restrict__ bv,
    const float* __restrict__ qn, const float* __restrict__ kn,
    unsigned short* __restrict__ qv, unsigned short* __restrict__ kv,
    unsigned short* __restrict__ vv)
{
  __shared__ unsigned short As[2][128 * 64];   // two 64-col panels, 32 KB
  __shared__ unsigned short Bs[2][64 * 64];    // two 64-col panels, 16 KB

  // XCD-locality decode: bid = g*8 + xcd; bx = xcd*4 + (g&3); y = g>>2.
  const int bid = blockIdx.x;
  const int xcd = bid & 7;
  const int g   = bid >> 3;            // 0..95
  const int bx  = xcd * 4 + (g & 3);   // 0..31 M-tile
  const int y   = g >> 2;              // 0..23

  const unsigned short* wt; const float* bias; unsigned short* outp; int opitch, col0, mode;
  if (y < 16)      { wt = WqT + (size_t)y * 64 * D_;        bias = bq + y * 64;        outp = qv; opitch = D_;   col0 = y * 64;        mode = 0; }
  else if (y < 20) { wt = WkT + (size_t)(y - 16) * 64 * D_; bias = bk + (y - 16) * 64; outp = kv; opitch = KVD_; col0 = (y - 16) * 64; mode = 1; }
  else             { wt = WvT + (size_t)(y - 20) * 64 * D_; bias = bv + (y - 20) * 64; outp = vv; opitch = KVD_; col0 = (y - 20) * 64; mode = 2; }

  const int bm = bx * 128;
  const int tid = threadIdx.x;
  const int w = tid >> 6, lane = tid & 63, quad = lane >> 4, l16 = lane & 15;
  const int lr = lane >> 3;          // staged sub-row 0..7
  const int gc = (lane & 7) ^ lr;    // swizzled source chunk
  const int sw = l16 & 7;            // frag-read swizzle selector

  const unsigned short* gA = xh + (size_t)(bm + w * 8 + lr) * D_ + gc * 8;
  const unsigned short* gB = wt + (size_t)(w * 8 + lr) * D_ + gc * 8;

  f32x4 acc[2][4];
#pragma unroll
  for (int i = 0; i < 2; ++i)
#pragma unroll
    for (int j = 0; j < 4; ++j) acc[i][j] = (f32x4){0.f, 0.f, 0.f, 0.f};

  for (int k0 = 0; k0 < D_; k0 += 128) {
    __syncthreads();
#pragma unroll
    for (int p = 0; p < 2; ++p) {
#pragma unroll
      for (int rd = 0; rd < 4; ++rd)
        dma16(gA + (size_t)rd * 32 * D_ + k0 + p * 64, &As[p][rd * 2048 + w * 512]);
#pragma unroll
      for (int rd = 0; rd < 2; ++rd)
        dma16(gB + (size_t)rd * 32 * D_ + k0 + p * 64, &Bs[p][rd * 2048 + w * 512]);
    }
    __syncthreads();

#pragma unroll
    for (int kk = 0; kk < 4; ++kk) {
      const int p = kk >> 1;
      const int slot = ((((kk & 1) * 4 + quad)) ^ sw) * 8;
      half8v fa[2], fb[4];
#pragma unroll
      for (int mb = 0; mb < 2; ++mb)
        fa[mb] = *(const half8v*)&As[p][(w * 32 + mb * 16 + l16) * 64 + slot];
#pragma unroll
      for (int nb = 0; nb < 4; ++nb)
        fb[nb] = *(const half8v*)&Bs[p][(nb * 16 + l16) * 64 + slot];
#pragma unroll
      for (int mb = 0; mb < 2; ++mb)
#pragma unroll
        for (int nb = 0; nb < 4; ++nb)
          acc[mb][nb] = __builtin_amdgcn_mfma_f32_16x16x32_f16(fa[mb], fb[nb], acc[mb][nb], 0, 0, 0);
    }
  }

  float bsv[4];
#pragma unroll
  for (int nb = 0; nb < 4; ++nb) bsv[nb] = bias[nb * 16 + l16];

  if (mode == 2) {   // V: bias + cast only
#pragma unroll
    for (int mb = 0; mb < 2; ++mb)
#pragma unroll
      for (int nb = 0; nb < 4; ++nb)
#pragma unroll
        for (int r = 0; r < 4; ++r) {
          const int row = bm + w * 32 + mb * 16 + quad * 4 + r;
          outp[(size_t)row * opitch + col0 + nb * 16 + l16] = f2h(acc[mb][nb][r] + bsv[nb]);
        }
    return;
  }

  // Q/K: RMSNorm (+learned w) + factored 3D RoPE, fp32 pre-rounding.
  const float* nwp = (mode == 0) ? qn : kn;
  float wv[4];
#pragma unroll
  for (int nb = 0; nb < 4; ++nb) wv[nb] = nwp[nb * 16 + l16];
  const float f_th = __powf(THETA_, -(float)(l16 & 7) / 8.0f);   // t/h segs, dd=16
  const float f_w  = __powf(THETA_, -(float)l16 / 16.0f);        // w seg,  dd=32
  const float oscale = (mode == 0) ? 0.125f * LOG2E_ : 1.0f;     // attn scale * log2e
  const bool first8 = (l16 & 8) == 0;

  float snw[4], csw[4];
#pragma unroll
  for (int r = 0; r < 4; ++r)
    __sincosf((float)(quad * 4 + r) * f_w, &snw[r], &csw[r]);

#pragma unroll
  for (int mb = 0; mb < 2; ++mb) {
    const int nbase = (bm + w * 32 + mb * 16) & (N_ - 1);
    float snt, cst, snh, csh;
    __sincosf((float)(nbase >> 8) * f_th, &snt, &cst);
    __sincosf((float)((nbase >> 4) & 15) * f_th, &snh, &csh);
#pragma unroll
    for (int r = 0; r < 4; ++r) {
      float v[4];
      float ss = 0.f;
#pragma unroll
      for (int nb = 0; nb < 4; ++nb) { v[nb] = acc[mb][nb][r] + bsv[nb]; ss += v[nb] * v[nb]; }
      ss += __shfl_xor(ss, 1, 64);
      ss += __shfl_xor(ss, 2, 64);
      ss += __shfl_xor(ss, 4, 64);
      ss += __shfl_xor(ss, 8, 64);
      const float rs = rsqrtf(ss * (1.0f / 64.0f) + EPS_);
#pragma unroll
      for (int nb = 0; nb < 4; ++nb) v[nb] *= rs * wv[nb];

      const float p0 = __shfl_xor(v[0], 8, 64);
      const float p1 = __shfl_xor(v[1], 8, 64);
      const float o0 = v[0] * cst + (first8 ? -p0 : p0) * snt;
      const float o1 = v[1] * csh + (first8 ? -p1 : p1) * snh;
      const float o2 = v[2] * csw[r] - v[3] * snw[r];
      const float o3 = v[3] * csw[r] + v[2] * snw[r];

      const int row = bm + w * 32 + mb * 16 + quad * 4 + r;
      const size_t ob = (size_t)row * opitch + col0 + l16;
      outp[ob]      = f2h(o0 * oscale);
      outp[ob + 16] = f2h(o1 * oscale);
      outp[ob + 32] = f2h(o2 * oscale);
      outp[ob + 48] = f2h(o3 * oscale);
    }
  }
}

// ---------------------------------------------------------------------------
// Output projection: A = O (single f16), B = 64*Wo^T as f16 hi+lo (~22 bits).
// 128x64 tile, 4 waves all-M, XCD decode. NEW (r11): BK=128 panel pairing
// (same scheme as gemm_qkv): K-loop 16 -> 8 steps, LDS 32 -> 64 KB (2/CU =
// grid average, unchanged). Epilogue multiplies by 1/64 and adds bias.
// ---------------------------------------------------------------------------
__global__ __launch_bounds__(256) void gemm_o(
    const unsigned short* __restrict__ ag,
    const unsigned short* __restrict__ WTh, const unsigned short* __restrict__ WTl,
    const float* __restrict__ bo, float* __restrict__ out)
{
  __shared__ unsigned short As[2][128 * 64];                 // 32 KB
  __shared__ unsigned short Bh[2][64 * 64], Bl[2][64 * 64];  // 16 KB each

  const int bid = blockIdx.x;
  const int xcd = bid & 7;
  const int g   = bid >> 3;            // 0..63
  const int bx  = xcd * 4 + (g & 3);   // 0..31
  const int by  = g >> 2;              // 0..15

  const int bm = bx * 128, bn = by * 64;
  const int tid = threadIdx.x;
  const int w = tid >> 6, lane = tid & 63, quad = lane >> 4, l16 = lane & 15;
  const int lr = lane >> 3;
  const int gc = (lane & 7) ^ lr;
  const int sw = l16 & 7;

  const unsigned short* gA  = ag  + (size_t)(bm + w * 8 + lr) * D_ + gc * 8;
  const unsigned short* gBh = WTh + (size_t)(bn + w * 8 + lr) * D_ + gc * 8;
  const unsigned short* gBl = WTl + (size_t)(bn + w * 8 + lr) * D_ + gc * 8;

  f32x4 acc[2][4];
#pragma unroll
  for (int i = 0; i < 2; ++i)
#pragma unroll
    for (int j = 0; j < 4; ++j) acc[i][j] = (f32x4){0.f, 0.f, 0.f, 0.f};

  for (int k0 = 0; k0 < D_; k0 += 128) {
    __syncthreads();
#pragma unroll
    for (int p = 0; p < 2; ++p) {
#pragma unroll
      for (int rd = 0; rd < 4; ++rd)
        dma16(gA + (size_t)rd * 32 * D_ + k0 + p * 64, &As[p][rd * 2048 + w * 512]);
#pragma unroll
      for (int rd = 0; rd < 2; ++rd) {
        dma16(gBh + (size_t)rd * 32 * D_ + k0 + p * 64, &Bh[p][rd * 2048 + w * 512]);
        dma16(gBl + (size_t)rd * 32 * D_ + k0 + p * 64, &Bl[p][rd * 2048 + w * 512]);
      }
    }
    __syncthreads();

#pragma unroll
    for (int kk = 0; kk < 4; ++kk) {
      const int p = kk >> 1;
      const int slot = ((((kk & 1) * 4 + quad)) ^ sw) * 8;
      half8v fa[2], fbh[4], fbl[4];
#pragma unroll
      for (int mb = 0; mb < 2; ++mb)
        fa[mb] = *(const half8v*)&As[p][(w * 32 + mb * 16 + l16) * 64 + slot];
#pragma unroll
      for (int nb = 0; nb < 4; ++nb) {
        const int ro = (nb * 16 + l16) * 64 + slot;
        fbh[nb] = *(const half8v*)&Bh[p][ro];
        fbl[nb] = *(const half8v*)&Bl[p][ro];
      }
#pragma unroll
      for (int mb = 0; mb < 2; ++mb)
#pragma unroll
        for (int nb = 0; nb < 4; ++nb) {
          acc[mb][nb] = __builtin_amdgcn_mfma_f32_16x16x32_f16(fa[mb], fbl[nb], acc[mb][nb], 0, 0, 0);
          acc[mb][nb] = __builtin_amdgcn_mfma_f32_16x16x32_f16(fa[mb], fbh[nb], acc[mb][nb], 0, 0, 0);
        }
    }
  }

  float bsv[4];
#pragma unroll
  for (int nb = 0; nb < 4; ++nb) bsv[nb] = bo[bn + nb * 16 + l16];
#pragma unroll
  for (int mb = 0; mb < 2; ++mb)
#pragma unroll
    for (int nb = 0; nb < 4; ++nb)
#pragma unroll
      for (int r = 0; r < 4; ++r) {
        const int row = bm + w * 32 + mb * 16 + quad * 4 + r;
        const int col = bn + nb * 16 + l16;
        out[(size_t)row * D_ + col] = acc[mb][nb][r] * 0.015625f + bsv[nb];
      }
}

// ---------------------------------------------------------------------------
// MFMA flash attention — P-in-register, 8-wave / 256-row q-tile (r10 form,
// frozen: XCD decode keeps FETCH at 6.2 MB; dur 46.5-48.4 band).
// ---------------------------------------------------------------------------
__global__ __launch_bounds__(512, 2) void attn_mfma(
    const unsigned short* __restrict__ qg,
    const unsigned short* __restrict__ kg,
    const unsigned short* __restrict__ vg,
    unsigned short* __restrict__ og)
{
  __shared__ unsigned short Ks[2][128 * 64];   // swizzled, 2x16 KB
  __shared__ unsigned short Vt[2][64][136];    // [dim][key'], 2x17 KB

  // decode: bid = g*8 + xcd; xcd = b*4 + kvh; g = qt*4 + hsub (bijective, 256)
  const int bid = blockIdx.x;
  const int xcd = bid & 7;
  const int g   = bid >> 3;          // 0..31
  const int b   = xcd >> 2;
  const int kvh = xcd & 3;
  const int h   = kvh * 4 + (g & 3);
  const int qt  = g >> 2;            // 0..7

  const int tid  = threadIdx.x;
  const int w    = tid >> 6;         // 0..7
  const int lane = tid & 63;
  const int quad = lane >> 4;
  const int l16  = lane & 15;
  const int lr = lane >> 3;
  const int gc = (lane & 7) ^ lr;
  const int sw = l16 & 7;

  // Q frags (B-operand: lane l16 = q-row, 8 dims at quad*8 / 32+quad*8).
  half8v aq[2][2];
#pragma unroll
  for (int qb = 0; qb < 2; ++qb) {
    const int qrow = qt * 256 + w * 32 + qb * 16 + l16;
    const unsigned short* qptr =
        qg + ((size_t)(b * N_ + qrow) * D_) + h * HD_ + quad * 8;
    aq[qb][0] = *(const half8v*)(qptr);
    aq[qb][1] = *(const half8v*)(qptr + 32);
  }

  // O^T accumulators: o_[qb][nb][r] = O[dim=nb*16+quad*4+r][qrow(l16)]
  f32x4 o_[2][4];
  float lrow[2] = {0.f, 0.f};        // per-lane softmax denom (q-row local)
#pragma unroll
  for (int qb = 0; qb < 2; ++qb)
#pragma unroll
    for (int i = 0; i < 4; ++i) o_[qb][i] = (f32x4){0.f, 0.f, 0.f, 0.f};

  // K DMA source: 2 dma16/wave x 8 waves cover 128 rows (row = rd*64 + w*8 + lr)
  const unsigned short* gK =
      kg + ((size_t)(b * N_) + w * 8 + lr) * KVD_ + kvh * HD_ + gc * 8;

  // V staging with the P-frag key' permutation:
  //   within-half key K (bits k5..k0) -> pos = k5*32 + (k3k2)*8 + k4*4 + k1k0
  // 512 threads: vhh = tid>>8 picks the 64-key half; thread loads key pair
  // (K0, K0+1), K0 = 2*vj + 32*vh, dims 8vs..8vs+7, packs one u32/dim at
  // column vhh*64 + pos(K0).
  const int vj  = tid & 15;
  const int vh  = (tid >> 4) & 1;
  const int vs  = (tid >> 5) & 7;
  const int vhh = tid >> 8;          // 0..1
  const int vcol = vhh * 64 + vh * 32 +
                   ((vj >> 1) & 3) * 8 + ((vj >> 3) & 1) * 4 + 2 * (vj & 1);
  const unsigned short* gV =
      vg + (size_t)(b * N_ + vhh * 64 + 2 * vj + 32 * vh) * KVD_ + kvh * HD_ + 8 * vs;

  // ---- prologue: stage tile 0, prefetch V tile 1 ----
#pragma unroll
  for (int rd = 0; rd < 2; ++rd)
    dma16(gK + (size_t)(rd * 64) * KVD_, &Ks[0][rd * 4096 + w * 512]);
  ushort8v va0 = *(const ushort8v*)(gV);
  ushort8v va1 = *(const ushort8v*)(gV + KVD_);
#pragma unroll
  for (int i = 0; i < 8; ++i)
    *(unsigned int*)&Vt[0][8 * vs + i][vcol] =
        (unsigned int)va0[i] | ((unsigned int)va1[i] << 16);
  {
    const unsigned short* p = gV + (size_t)128 * KVD_;
    va0 = *(const ushort8v*)(p);
    va1 = *(const ushort8v*)(p + KVD_);
  }
  __syncthreads();

  for (int kt = 0; kt < 16; ++kt) {
    const int cur = kt & 1;
    // stage tile kt+1 into the other buffer; DMA/ds_writes complete during
    // this tile's compute and are drained by the end-of-loop barrier.
    if (kt < 15) {
#pragma unroll
      for (int rd = 0; rd < 2; ++rd)
        dma16(gK + (size_t)((kt + 1) * 128 + rd * 64) * KVD_,
              &Ks[cur ^ 1][rd * 4096 + w * 512]);
#pragma unroll
      for (int i = 0; i < 8; ++i)
        *(unsigned int*)&Vt[cur ^ 1][8 * vs + i][vcol] =
            (unsigned int)va0[i] | ((unsigned int)va1[i] << 16);
      if (kt < 14) {
        const unsigned short* p = gV + (size_t)(kt + 2) * 128 * KVD_;
        va0 = *(const ushort8v*)(p);
        va1 = *(const ushort8v*)(p + KVD_);
      }
    }

    // ---- compute tile kt from Ks[cur], Vt[cur] ----
#pragma unroll
    for (int hh = 0; hh < 2; ++hh) {
      // S^T = K·Q^T : lane holds P[key=nb*16+quad*4+r][qrow=l16]
      f32x4 s[2][4];
#pragma unroll
      for (int nb = 0; nb < 4; ++nb) {
        const int kr = (hh * 64 + nb * 16 + l16) * 64;
        const half8v b0 = *(const half8v*)&Ks[cur][kr + (quad ^ sw) * 8];
        const half8v b1 = *(const half8v*)&Ks[cur][kr + ((4 + quad) ^ sw) * 8];
#pragma unroll
        for (int qb = 0; qb < 2; ++qb) {
          f32x4 z = (f32x4){0.f, 0.f, 0.f, 0.f};
          z = __builtin_amdgcn_mfma_f32_16x16x32_f16(b0, aq[qb][0], z, 0, 0, 0);
          s[qb][nb] = __builtin_amdgcn_mfma_f32_16x16x32_f16(b1, aq[qb][1], z, 0, 0, 0);
        }
      }

      // exp2 + pack to P-frags in registers (no LDS round-trip).
      // pf[qb][kc][j]: key K = (2kc+(j>>2))*16 + quad*4 + (j&3)
      half8v pf[2][2];
#pragma unroll
      for (int qb = 0; qb < 2; ++qb) {
        float ls = 0.f;
#pragma unroll
        for (int nb = 0; nb < 4; ++nb) {
          const float p0 = EXP2F(s[qb][nb][0]);
          const float p1 = EXP2F(s[qb][nb][1]);
          const float p2 = EXP2F(s[qb][nb][2]);
          const float p3 = EXP2F(s[qb][nb][3]);
          ls += (p0 + p1) + (p2 + p3);
          const int kc = nb >> 1, jo = (nb & 1) * 4;
          pf[qb][kc][jo + 0] = (_Float16)p0;
          pf[qb][kc][jo + 1] = (_Float16)p1;
          pf[qb][kc][jo + 2] = (_Float16)p2;
          pf[qb][kc][jo + 3] = (_Float16)p3;
        }
        lrow[qb] += ls;
      }

      // O^T += V^T · P^T ; V-frags shared across both q-subtiles
#pragma unroll
      for (int kc = 0; kc < 2; ++kc)
#pragma unroll
        for (int nb = 0; nb < 4; ++nb) {
          const half8v bv =
              *(const half8v*)&Vt[cur][nb * 16 + l16][hh * 64 + kc * 32 + quad * 8];
#pragma unroll
          for (int qb = 0; qb < 2; ++qb)
            o_[qb][nb] = __builtin_amdgcn_mfma_f32_16x16x32_f16(bv, pf[qb][kc], o_[qb][nb], 0, 0, 0);
        }
    }
    __syncthreads();
  }

  // epilogue: denom reduce across quads (same l16), write O^T as 8B chunks
#pragma unroll
  for (int qb = 0; qb < 2; ++qb) {
    float l = lrow[qb];
    l += __shfl_xor(l, 16, 64);
    l += __shfl_xor(l, 32, 64);
    const float inv = 1.0f / l;
    const int qrow = qt * 256 + w * 32 + qb * 16 + l16;
    const size_t base = (size_t)(b * N_ + qrow) * D_ + h * HD_;
#pragma unroll
    for (int nb = 0; nb < 4; ++nb) {
      half4v pk;
#pragma unroll
      for (int r = 0; r < 4; ++r) pk[r] = (_Float16)(o_[qb][nb][r] * inv);
      *(half4v*)&og[base + nb * 16 + quad * 4] = pk;
    }
  }
}

// ---------------------------------------------------------------------------
extern "C" void kernel_launch(void* const* d_in, const int* in_sizes, int n_in,
                              void* d_out, int out_size, void* d_ws, size_t ws_size,
                              hipStream_t stream) {
  const float* x  = (const float*)d_in[0];
  const float* Wq = (const float*)d_in[1];
  const float* bq = (const float*)d_in[2];
  const float* Wk = (const float*)d_in[3];
  const float* bk = (const float*)d_in[4];
  const float* Wv = (const float*)d_in[5];
  const float* bv = (const float*)d_in[6];
  const float* Wo = (const float*)d_in[7];
  const float* bo = (const float*)d_in[8];
  const float* qn = (const float*)d_in[9];
  const float* kn = (const float*)d_in[10];
  float* out = (float*)d_out;

  // Workspace (u16 units, ~27 MB):
  //  xh(4M) qv(4M) kv(1M) vv(1M) WqT(1M) WkT(.25M) WvT(.25M) WoTh(1M) WoTl(1M)
  //  attention output og aliases xh (dead after gemm_qkv).
  const size_t M4 = (size_t)BN_ * D_;
  const size_t M1 = (size_t)BN_ * KVD_;
  unsigned short* xh  = (unsigned short*)d_ws;
  unsigned short* qv  = xh + M4;
  unsigned short* kv  = qv + M4;
  unsigned short* vv  = kv + M1;
  unsigned short* WqT = vv + M1;
  unsigned short* WkT = WqT + (size_t)D_ * D_;
  unsigned short* WvT = WkT + (size_t)D_ * KVD_;
  unsigned short* WoTh = WvT + (size_t)D_ * KVD_;
  unsigned short* WoTl = WoTh + (size_t)D_ * D_;
  unsigned short* og  = xh;   // alias

  const dim3 blk(256);

  // 1) cast + all weight transposes in one launch
  prep<<<dim3(4608), blk, 0, stream>>>(x, Wq, Wk, Wv, Wo, xh, WqT, WkT, WvT, WoTh, WoTl);

  // 2) fused QKV projection + RMSNorm + RoPE (BK=128 panels, XCD grid 768)
  gemm_qkv<<<dim3(768), blk, 0, stream>>>(xh, WqT, WkT, WvT, bq, bk, bv, qn, kn, qv, kv, vv);

  // 3) P-in-register MFMA flash attention (r10 form, XCD-swizzled, 256 blocks)
  attn_mfma<<<dim3(256), dim3(512), 0, stream>>>(qv, kv, vv, og);

  // 4) output projection (BK=128 panels, XCD grid 512)
  gemm_o<<<dim3(512), blk, 0, stream>>>(og, WoTh, WoTl, bo, out);
}

// Round 12
// 173.192 us; speedup vs baseline: 1.1122x; 1.0034x over previous
//
#include <hip/hip_runtime.h>
#include <hip/hip_bf16.h>
#include <math.h>

// Problem constants (fixed by the reference file)
constexpr int B_   = 2;
constexpr int N_   = 2048;   // T*HS*WS = 8*16*16
constexpr int D_   = 1024;
constexpr int NH_  = 16;
constexpr int NKV_ = 4;
constexpr int HD_  = 64;
constexpr int BN_  = 4096;   // B_*N_
constexpr int KVD_ = NKV_ * HD_;  // 256
constexpr float EPS_ = 1e-6f;
constexpr float THETA_ = 10000.0f;
constexpr float LOG2E_ = 1.4426950408889634f;

typedef _Float16 half8v __attribute__((ext_vector_type(8)));
typedef _Float16 half4v __attribute__((ext_vector_type(4)));
typedef unsigned short ushort8v __attribute__((ext_vector_type(8)));
typedef float f32x4 __attribute__((ext_vector_type(4)));

static __device__ __forceinline__ unsigned short f2h(float f) {
  union { _Float16 h; unsigned short u; } v; v.h = (_Float16)f; return v.u;
}
static __device__ __forceinline__ float h2f(unsigned short u) {
  union { unsigned short u; _Float16 h; } v; v.u = u; return (float)v.h;
}

// Hardware 2^x. q is pre-scaled by log2(e) so exp(s_raw) == exp2(s).
#if __has_builtin(__builtin_amdgcn_exp2f)
#define EXP2F(x) __builtin_amdgcn_exp2f(x)
#else
#define EXP2F(x) __expf((x) * 0.6931471805599453f)
#endif

// global -> LDS direct DMA, 16 B per lane. LDS dest = wave-uniform base +
// lane*16 (m104). The per-lane GLOBAL address is free, which lets us store an
// XOR-swizzled layout (chunk c of row r lands at slot c^(r&7)) so the b128
// fragment reads are conflict-free without padding.
static __device__ __forceinline__ void dma16(const unsigned short* g,
                                             unsigned short* l) {
  __builtin_amdgcn_global_load_lds(
      (const __attribute__((address_space(1))) unsigned int*)g,
      (__attribute__((address_space(3))) unsigned int*)l, 16, 0, 0);
}

// ---------------------------------------------------------------------------
// prep: one launch doing x->f16 cast + all 4 weight transposes. r12: Wo is a
// SINGLE f16 transpose (scale 1.0, no lo residual) — error analysis: the
// pipeline absmax (pinned at 2^-11) is dominated by f16 rounding of O/out,
// not Wo precision; the lo-path contributed ~6e-5 std, below that floor.
// ---------------------------------------------------------------------------
static __device__ __forceinline__ void wtrans_tile(
    const float* __restrict__ W, int Nw, int K, float scale,
    unsigned short* __restrict__ WTh, unsigned short* __restrict__ WTl,
    int bx, int by, bool lo)
{
  __shared__ float tile[32][33];
  const int k0 = bx * 32, n0 = by * 32;
  const int c = threadIdx.x & 31, rb = threadIdx.x >> 5;
#pragma unroll
  for (int i = 0; i < 4; ++i) {
    const int r = rb + i * 8;
    tile[r][c] = W[(size_t)(k0 + r) * Nw + n0 + c];
  }
  __syncthreads();
#pragma unroll
  for (int i = 0; i < 4; ++i) {
    const int r = rb + i * 8;
    const float v = tile[c][r] * scale;   // = W[k0+c][n0+r] * scale
    const size_t o = (size_t)(n0 + r) * K + k0 + c;
    const unsigned short hi = f2h(v);
    WTh[o] = hi;
    if (lo) WTl[o] = f2h(v - h2f(hi));
  }
}

__global__ __launch_bounds__(256) void prep(
    const float* __restrict__ x,
    const float* __restrict__ Wq, const float* __restrict__ Wk,
    const float* __restrict__ Wv, const float* __restrict__ Wo,
    unsigned short* __restrict__ xh,
    unsigned short* __restrict__ WqT, unsigned short* __restrict__ WkT,
    unsigned short* __restrict__ WvT,
    unsigned short* __restrict__ WoT)
{
  const int bid = blockIdx.x;
  if (bid < 2048) {
    const int i = (bid * 256 + threadIdx.x) * 8;
    const float4 v0 = *(const float4*)(x + i);
    const float4 v1 = *(const float4*)(x + i + 4);
    ushort8v o;
    o[0] = f2h(v0.x); o[1] = f2h(v0.y); o[2] = f2h(v0.z); o[3] = f2h(v0.w);
    o[4] = f2h(v1.x); o[5] = f2h(v1.y); o[6] = f2h(v1.z); o[7] = f2h(v1.w);
    *(ushort8v*)(xh + i) = o;
  } else if (bid < 3072) {
    const int l = bid - 2048;
    wtrans_tile(Wq, D_, D_, 1.0f, WqT, nullptr, l & 31, l >> 5, false);
  } else if (bid < 3328) {
    const int l = bid - 3072;
    wtrans_tile(Wk, KVD_, D_, 1.0f, WkT, nullptr, l & 31, l >> 5, false);
  } else if (bid < 3584) {
    const int l = bid - 3328;
    wtrans_tile(Wv, KVD_, D_, 1.0f, WvT, nullptr, l & 31, l >> 5, false);
  } else {
    const int l = bid - 3584;
    wtrans_tile(Wo, D_, D_, 1.0f, WoT, nullptr, l & 31, l >> 5, false);
  }
}

// ---------------------------------------------------------------------------
// Fused QKV projection + RMSNorm + 3D RoPE in the epilogue (r11 form, frozen).
// 128x64 tile, 4 waves all-M, BK=128 panel pairing, XCD-locality decode.
// Q output carries log2(e) so attention can use hw exp2.
// ---------------------------------------------------------------------------
__global__ __launch_bounds__(256) void gemm_qkv(
    const unsigned short* __restrict__ xh,
    const unsigned short* __restrict__ WqT, const unsigned short* __restrict__ WkT,
    const unsigned short* __restrict__ WvT,
    const float* __restrict__ bq, const float* __restrict__ bk, const float* __restrict__ bv,
    const float* __restrict__ qn, const float* __restrict__ kn,
    unsigned short* __restrict__ qv, unsigned short* __restrict__ kv,
    unsigned short* __restrict__ vv)
{
  __shared__ unsigned short As[2][128 * 64];   // two 64-col panels, 32 KB
  __shared__ unsigned short Bs[2][64 * 64];    // two 64-col panels, 16 KB

  // XCD-locality decode: bid = g*8 + xcd; bx = xcd*4 + (g&3); y = g>>2.
  const int bid = blockIdx.x;
  const int xcd = bid & 7;
  const int g   = bid >> 3;            // 0..95
  const int bx  = xcd * 4 + (g & 3);   // 0..31 M-tile
  const int y   = g >> 2;              // 0..23

  const unsigned short* wt; const float* bias; unsigned short* outp; int opitch, col0, mode;
  if (y < 16)      { wt = WqT + (size_t)y * 64 * D_;        bias = bq + y * 64;        outp = qv; opitch = D_;   col0 = y * 64;        mode = 0; }
  else if (y < 20) { wt = WkT + (size_t)(y - 16) * 64 * D_; bias = bk + (y - 16) * 64; outp = kv; opitch = KVD_; col0 = (y - 16) * 64; mode = 1; }
  else             { wt = WvT + (size_t)(y - 20) * 64 * D_; bias = bv + (y - 20) * 64; outp = vv; opitch = KVD_; col0 = (y - 20) * 64; mode = 2; }

  const int bm = bx * 128;
  const int tid = threadIdx.x;
  const int w = tid >> 6, lane = tid & 63, quad = lane >> 4, l16 = lane & 15;
  const int lr = lane >> 3;          // staged sub-row 0..7
  const int gc = (lane & 7) ^ lr;    // swizzled source chunk
  const int sw = l16 & 7;            // frag-read swizzle selector

  const unsigned short* gA = xh + (size_t)(bm + w * 8 + lr) * D_ + gc * 8;
  const unsigned short* gB = wt + (size_t)(w * 8 + lr) * D_ + gc * 8;

  f32x4 acc[2][4];
#pragma unroll
  for (int i = 0; i < 2; ++i)
#pragma unroll
    for (int j = 0; j < 4; ++j) acc[i][j] = (f32x4){0.f, 0.f, 0.f, 0.f};

  for (int k0 = 0; k0 < D_; k0 += 128) {
    __syncthreads();
#pragma unroll
    for (int p = 0; p < 2; ++p) {
#pragma unroll
      for (int rd = 0; rd < 4; ++rd)
        dma16(gA + (size_t)rd * 32 * D_ + k0 + p * 64, &As[p][rd * 2048 + w * 512]);
#pragma unroll
      for (int rd = 0; rd < 2; ++rd)
        dma16(gB + (size_t)rd * 32 * D_ + k0 + p * 64, &Bs[p][rd * 2048 + w * 512]);
    }
    __syncthreads();

#pragma unroll
    for (int kk = 0; kk < 4; ++kk) {
      const int p = kk >> 1;
      const int slot = ((((kk & 1) * 4 + quad)) ^ sw) * 8;
      half8v fa[2], fb[4];
#pragma unroll
      for (int mb = 0; mb < 2; ++mb)
        fa[mb] = *(const half8v*)&As[p][(w * 32 + mb * 16 + l16) * 64 + slot];
#pragma unroll
      for (int nb = 0; nb < 4; ++nb)
        fb[nb] = *(const half8v*)&Bs[p][(nb * 16 + l16) * 64 + slot];
#pragma unroll
      for (int mb = 0; mb < 2; ++mb)
#pragma unroll
        for (int nb = 0; nb < 4; ++nb)
          acc[mb][nb] = __builtin_amdgcn_mfma_f32_16x16x32_f16(fa[mb], fb[nb], acc[mb][nb], 0, 0, 0);
    }
  }

  float bsv[4];
#pragma unroll
  for (int nb = 0; nb < 4; ++nb) bsv[nb] = bias[nb * 16 + l16];

  if (mode == 2) {   // V: bias + cast only
#pragma unroll
    for (int mb = 0; mb < 2; ++mb)
#pragma unroll
      for (int nb = 0; nb < 4; ++nb)
#pragma unroll
        for (int r = 0; r < 4; ++r) {
          const int row = bm + w * 32 + mb * 16 + quad * 4 + r;
          outp[(size_t)row * opitch + col0 + nb * 16 + l16] = f2h(acc[mb][nb][r] + bsv[nb]);
        }
    return;
  }

  // Q/K: RMSNorm (+learned w) + factored 3D RoPE, fp32 pre-rounding.
  const float* nwp = (mode == 0) ? qn : kn;
  float wv[4];
#pragma unroll
  for (int nb = 0; nb < 4; ++nb) wv[nb] = nwp[nb * 16 + l16];
  const float f_th = __powf(THETA_, -(float)(l16 & 7) / 8.0f);   // t/h segs, dd=16
  const float f_w  = __powf(THETA_, -(float)l16 / 16.0f);        // w seg,  dd=32
  const float oscale = (mode == 0) ? 0.125f * LOG2E_ : 1.0f;     // attn scale * log2e
  const bool first8 = (l16 & 8) == 0;

  float snw[4], csw[4];
#pragma unroll
  for (int r = 0; r < 4; ++r)
    __sincosf((float)(quad * 4 + r) * f_w, &snw[r], &csw[r]);

#pragma unroll
  for (int mb = 0; mb < 2; ++mb) {
    const int nbase = (bm + w * 32 + mb * 16) & (N_ - 1);
    float snt, cst, snh, csh;
    __sincosf((float)(nbase >> 8) * f_th, &snt, &cst);
    __sincosf((float)((nbase >> 4) & 15) * f_th, &snh, &csh);
#pragma unroll
    for (int r = 0; r < 4; ++r) {
      float v[4];
      float ss = 0.f;
#pragma unroll
      for (int nb = 0; nb < 4; ++nb) { v[nb] = acc[mb][nb][r] + bsv[nb]; ss += v[nb] * v[nb]; }
      ss += __shfl_xor(ss, 1, 64);
      ss += __shfl_xor(ss, 2, 64);
      ss += __shfl_xor(ss, 4, 64);
      ss += __shfl_xor(ss, 8, 64);
      const float rs = rsqrtf(ss * (1.0f / 64.0f) + EPS_);
#pragma unroll
      for (int nb = 0; nb < 4; ++nb) v[nb] *= rs * wv[nb];

      const float p0 = __shfl_xor(v[0], 8, 64);
      const float p1 = __shfl_xor(v[1], 8, 64);
      const float o0 = v[0] * cst + (first8 ? -p0 : p0) * snt;
      const float o1 = v[1] * csh + (first8 ? -p1 : p1) * snh;
      const float o2 = v[2] * csw[r] - v[3] * snw[r];
      const float o3 = v[3] * csw[r] + v[2] * snw[r];

      const int row = bm + w * 32 + mb * 16 + quad * 4 + r;
      const size_t ob = (size_t)row * opitch + col0 + l16;
      outp[ob]      = f2h(o0 * oscale);
      outp[ob + 16] = f2h(o1 * oscale);
      outp[ob + 32] = f2h(o2 * oscale);
      outp[ob + 48] = f2h(o3 * oscale);
    }
  }
}

// ---------------------------------------------------------------------------
// Output projection — r12: SINGLE-f16 Wo (lo residual dropped). Halves the
// MFMA count (one per fragment) and the B staging (2 dma16/panel/step), LDS
// 64 -> 48 KB (3 blocks/CU). 128x64 tile, BK=128 panels, XCD decode.
// ---------------------------------------------------------------------------
__global__ __launch_bounds__(256) void gemm_o(
    const unsigned short* __restrict__ ag,
    const unsigned short* __restrict__ WT,
    const float* __restrict__ bo, float* __restrict__ out)
{
  __shared__ unsigned short As[2][128 * 64];   // 32 KB
  __shared__ unsigned short Bs[2][64 * 64];    // 16 KB

  const int bid = blockIdx.x;
  const int xcd = bid & 7;
  const int g   = bid >> 3;            // 0..63
  const int bx  = xcd * 4 + (g & 3);   // 0..31
  const int by  = g >> 2;              // 0..15

  const int bm = bx * 128, bn = by * 64;
  const int tid = threadIdx.x;
  const int w = tid >> 6, lane = tid & 63, quad = lane >> 4, l16 = lane & 15;
  const int lr = lane >> 3;
  const int gc = (lane & 7) ^ lr;
  const int sw = l16 & 7;

  const unsigned short* gA = ag + (size_t)(bm + w * 8 + lr) * D_ + gc * 8;
  const unsigned short* gB = WT + (size_t)(bn + w * 8 + lr) * D_ + gc * 8;

  f32x4 acc[2][4];
#pragma unroll
  for (int i = 0; i < 2; ++i)
#pragma unroll
    for (int j = 0; j < 4; ++j) acc[i][j] = (f32x4){0.f, 0.f, 0.f, 0.f};

  for (int k0 = 0; k0 < D_; k0 += 128) {
    __syncthreads();
#pragma unroll
    for (int p = 0; p < 2; ++p) {
#pragma unroll
      for (int rd = 0; rd < 4; ++rd)
        dma16(gA + (size_t)rd * 32 * D_ + k0 + p * 64, &As[p][rd * 2048 + w * 512]);
#pragma unroll
      for (int rd = 0; rd < 2; ++rd)
        dma16(gB + (size_t)rd * 32 * D_ + k0 + p * 64, &Bs[p][rd * 2048 + w * 512]);
    }
    __syncthreads();

#pragma unroll
    for (int kk = 0; kk < 4; ++kk) {
      const int p = kk >> 1;
      const int slot = ((((kk & 1) * 4 + quad)) ^ sw) * 8;
      half8v fa[2], fb[4];
#pragma unroll
      for (int mb = 0; mb < 2; ++mb)
        fa[mb] = *(const half8v*)&As[p][(w * 32 + mb * 16 + l16) * 64 + slot];
#pragma unroll
      for (int nb = 0; nb < 4; ++nb)
        fb[nb] = *(const half8v*)&Bs[p][(nb * 16 + l16) * 64 + slot];
#pragma unroll
      for (int mb = 0; mb < 2; ++mb)
#pragma unroll
        for (int nb = 0; nb < 4; ++nb)
          acc[mb][nb] = __builtin_amdgcn_mfma_f32_16x16x32_f16(fa[mb], fb[nb], acc[mb][nb], 0, 0, 0);
    }
  }

  float bsv[4];
#pragma unroll
  for (int nb = 0; nb < 4; ++nb) bsv[nb] = bo[bn + nb * 16 + l16];
#pragma unroll
  for (int mb = 0; mb < 2; ++mb)
#pragma unroll
    for (int nb = 0; nb < 4; ++nb)
#pragma unroll
      for (int r = 0; r < 4; ++r) {
        const int row = bm + w * 32 + mb * 16 + quad * 4 + r;
        const int col = bn + nb * 16 + l16;
        out[(size_t)row * D_ + col] = acc[mb][nb][r] + bsv[nb];
      }
}

// ---------------------------------------------------------------------------
// MFMA flash attention — P-in-register, 8-wave / 256-row q-tile (r10 form,
// frozen: XCD decode keeps FETCH at 6.2 MB; dur 46.5-48.6 band).
// ---------------------------------------------------------------------------
__global__ __launch_bounds__(512, 2) void attn_mfma(
    const unsigned short* __restrict__ qg,
    const unsigned short* __restrict__ kg,
    const unsigned short* __restrict__ vg,
    unsigned short* __restrict__ og)
{
  __shared__ unsigned short Ks[2][128 * 64];   // swizzled, 2x16 KB
  __shared__ unsigned short Vt[2][64][136];    // [dim][key'], 2x17 KB

  // decode: bid = g*8 + xcd; xcd = b*4 + kvh; g = qt*4 + hsub (bijective, 256)
  const int bid = blockIdx.x;
  const int xcd = bid & 7;
  const int g   = bid >> 3;          // 0..31
  const int b   = xcd >> 2;
  const int kvh = xcd & 3;
  const int h   = kvh * 4 + (g & 3);
  const int qt  = g >> 2;            // 0..7

  const int tid  = threadIdx.x;
  const int w    = tid >> 6;         // 0..7
  const int lane = tid & 63;
  const int quad = lane >> 4;
  const int l16  = lane & 15;
  const int lr = lane >> 3;
  const int gc = (lane & 7) ^ lr;
  const int sw = l16 & 7;

  // Q frags (B-operand: lane l16 = q-row, 8 dims at quad*8 / 32+quad*8).
  half8v aq[2][2];
#pragma unroll
  for (int qb = 0; qb < 2; ++qb) {
    const int qrow = qt * 256 + w * 32 + qb * 16 + l16;
    const unsigned short* qptr =
        qg + ((size_t)(b * N_ + qrow) * D_) + h * HD_ + quad * 8;
    aq[qb][0] = *(const half8v*)(qptr);
    aq[qb][1] = *(const half8v*)(qptr + 32);
  }

  // O^T accumulators: o_[qb][nb][r] = O[dim=nb*16+quad*4+r][qrow(l16)]
  f32x4 o_[2][4];
  float lrow[2] = {0.f, 0.f};        // per-lane softmax denom (q-row local)
#pragma unroll
  for (int qb = 0; qb < 2; ++qb)
#pragma unroll
    for (int i = 0; i < 4; ++i) o_[qb][i] = (f32x4){0.f, 0.f, 0.f, 0.f};

  // K DMA source: 2 dma16/wave x 8 waves cover 128 rows (row = rd*64 + w*8 + lr)
  const unsigned short* gK =
      kg + ((size_t)(b * N_) + w * 8 + lr) * KVD_ + kvh * HD_ + gc * 8;

  // V staging with the P-frag key' permutation:
  //   within-half key K (bits k5..k0) -> pos = k5*32 + (k3k2)*8 + k4*4 + k1k0
  // 512 threads: vhh = tid>>8 picks the 64-key half; thread loads key pair
  // (K0, K0+1), K0 = 2*vj + 32*vh, dims 8vs..8vs+7, packs one u32/dim at
  // column vhh*64 + pos(K0).
  const int vj  = tid & 15;
  const int vh  = (tid >> 4) & 1;
  const int vs  = (tid >> 5) & 7;
  const int vhh = tid >> 8;          // 0..1
  const int vcol = vhh * 64 + vh * 32 +
                   ((vj >> 1) & 3) * 8 + ((vj >> 3) & 1) * 4 + 2 * (vj & 1);
  const unsigned short* gV =
      vg + (size_t)(b * N_ + vhh * 64 + 2 * vj + 32 * vh) * KVD_ + kvh * HD_ + 8 * vs;

  // ---- prologue: stage tile 0, prefetch V tile 1 ----
#pragma unroll
  for (int rd = 0; rd < 2; ++rd)
    dma16(gK + (size_t)(rd * 64) * KVD_, &Ks[0][rd * 4096 + w * 512]);
  ushort8v va0 = *(const ushort8v*)(gV);
  ushort8v va1 = *(const ushort8v*)(gV + KVD_);
#pragma unroll
  for (int i = 0; i < 8; ++i)
    *(unsigned int*)&Vt[0][8 * vs + i][vcol] =
        (unsigned int)va0[i] | ((unsigned int)va1[i] << 16);
  {
    const unsigned short* p = gV + (size_t)128 * KVD_;
    va0 = *(const ushort8v*)(p);
    va1 = *(const ushort8v*)(p + KVD_);
  }
  __syncthreads();

  for (int kt = 0; kt < 16; ++kt) {
    const int cur = kt & 1;
    // stage tile kt+1 into the other buffer; DMA/ds_writes complete during
    // this tile's compute and are drained by the end-of-loop barrier.
    if (kt < 15) {
#pragma unroll
      for (int rd = 0; rd < 2; ++rd)
        dma16(gK + (size_t)((kt + 1) * 128 + rd * 64) * KVD_,
              &Ks[cur ^ 1][rd * 4096 + w * 512]);
#pragma unroll
      for (int i = 0; i < 8; ++i)
        *(unsigned int*)&Vt[cur ^ 1][8 * vs + i][vcol] =
            (unsigned int)va0[i] | ((unsigned int)va1[i] << 16);
      if (kt < 14) {
        const unsigned short* p = gV + (size_t)(kt + 2) * 128 * KVD_;
        va0 = *(const ushort8v*)(p);
        va1 = *(const ushort8v*)(p + KVD_);
      }
    }

    // ---- compute tile kt from Ks[cur], Vt[cur] ----
#pragma unroll
    for (int hh = 0; hh < 2; ++hh) {
      // S^T = K·Q^T : lane holds P[key=nb*16+quad*4+r][qrow=l16]
      f32x4 s[2][4];
#pragma unroll
      for (int nb = 0; nb < 4; ++nb) {
        const int kr = (hh * 64 + nb * 16 + l16) * 64;
        const half8v b0 = *(const half8v*)&Ks[cur][kr + (quad ^ sw) * 8];
        const half8v b1 = *(const half8v*)&Ks[cur][kr + ((4 + quad) ^ sw) * 8];
#pragma unroll
        for (int qb = 0; qb < 2; ++qb) {
          f32x4 z = (f32x4){0.f, 0.f, 0.f, 0.f};
          z = __builtin_amdgcn_mfma_f32_16x16x32_f16(b0, aq[qb][0], z, 0, 0, 0);
          s[qb][nb] = __builtin_amdgcn_mfma_f32_16x16x32_f16(b1, aq[qb][1], z, 0, 0, 0);
        }
      }

      // exp2 + pack to P-frags in registers (no LDS round-trip).
      // pf[qb][kc][j]: key K = (2kc+(j>>2))*16 + quad*4 + (j&3)
      half8v pf[2][2];
#pragma unroll
      for (int qb = 0; qb < 2; ++qb) {
        float ls = 0.f;
#pragma unroll
        for (int nb = 0; nb < 4; ++nb) {
          const float p0 = EXP2F(s[qb][nb][0]);
          const float p1 = EXP2F(s[qb][nb][1]);
          const float p2 = EXP2F(s[qb][nb][2]);
          const float p3 = EXP2F(s[qb][nb][3]);
          ls += (p0 + p1) + (p2 + p3);
          const int kc = nb >> 1, jo = (nb & 1) * 4;
          pf[qb][kc][jo + 0] = (_Float16)p0;
          pf[qb][kc][jo + 1] = (_Float16)p1;
          pf[qb][kc][jo + 2] = (_Float16)p2;
          pf[qb][kc][jo + 3] = (_Float16)p3;
        }
        lrow[qb] += ls;
      }

      // O^T += V^T · P^T ; V-frags shared across both q-subtiles
#pragma unroll
      for (int kc = 0; kc < 2; ++kc)
#pragma unroll
        for (int nb = 0; nb < 4; ++nb) {
          const half8v bv =
              *(const half8v*)&Vt[cur][nb * 16 + l16][hh * 64 + kc * 32 + quad * 8];
#pragma unroll
          for (int qb = 0; qb < 2; ++qb)
            o_[qb][nb] = __builtin_amdgcn_mfma_f32_16x16x32_f16(bv, pf[qb][kc], o_[qb][nb], 0, 0, 0);
        }
    }
    __syncthreads();
  }

  // epilogue: denom reduce across quads (same l16), write O^T as 8B chunks
#pragma unroll
  for (int qb = 0; qb < 2; ++qb) {
    float l = lrow[qb];
    l += __shfl_xor(l, 16, 64);
    l += __shfl_xor(l, 32, 64);
    const float inv = 1.0f / l;
    const int qrow = qt * 256 + w * 32 + qb * 16 + l16;
    const size_t base = (size_t)(b * N_ + qrow) * D_ + h * HD_;
#pragma unroll
    for (int nb = 0; nb < 4; ++nb) {
      half4v pk;
#pragma unroll
      for (int r = 0; r < 4; ++r) pk[r] = (_Float16)(o_[qb][nb][r] * inv);
      *(half4v*)&og[base + nb * 16 + quad * 4] = pk;
    }
  }
}

// ---------------------------------------------------------------------------
extern "C" void kernel_launch(void* const* d_in, const int* in_sizes, int n_in,
                              void* d_out, int out_size, void* d_ws, size_t ws_size,
                              hipStream_t stream) {
  const float* x  = (const float*)d_in[0];
  const float* Wq = (const float*)d_in[1];
  const float* bq = (const float*)d_in[2];
  const float* Wk = (const float*)d_in[3];
  const float* bk = (const float*)d_in[4];
  const float* Wv = (const float*)d_in[5];
  const float* bv = (const float*)d_in[6];
  const float* Wo = (const float*)d_in[7];
  const float* bo = (const float*)d_in[8];
  const float* qn = (const float*)d_in[9];
  const float* kn = (const float*)d_in[10];
  float* out = (float*)d_out;

  // Workspace (u16 units, ~26 MB):
  //  xh(4M) qv(4M) kv(1M) vv(1M) WqT(1M) WkT(.25M) WvT(.25M) WoT(1M)
  //  attention output og aliases xh (dead after gemm_qkv).
  const size_t M4 = (size_t)BN_ * D_;
  const size_t M1 = (size_t)BN_ * KVD_;
  unsigned short* xh  = (unsigned short*)d_ws;
  unsigned short* qv  = xh + M4;
  unsigned short* kv  = qv + M4;
  unsigned short* vv  = kv + M1;
  unsigned short* WqT = vv + M1;
  unsigned short* WkT = WqT + (size_t)D_ * D_;
  unsigned short* WvT = WkT + (size_t)D_ * KVD_;
  unsigned short* WoT = WvT + (size_t)D_ * KVD_;
  unsigned short* og  = xh;   // alias

  const dim3 blk(256);

  // 1) cast + all weight transposes in one launch
  prep<<<dim3(4608), blk, 0, stream>>>(x, Wq, Wk, Wv, Wo, xh, WqT, WkT, WvT, WoT);

  // 2) fused QKV projection + RMSNorm + RoPE (BK=128 panels, XCD grid 768)
  gemm_qkv<<<dim3(768), blk, 0, stream>>>(xh, WqT, WkT, WvT, bq, bk, bv, qn, kn, qv, kv, vv);

  // 3) P-in-register MFMA flash attention (r10 form, XCD-swizzled, 256 blocks)
  attn_mfma<<<dim3(256), dim3(512), 0, stream>>>(qv, kv, vv, og);

  // 4) output projection (single-f16 Wo, BK=128 panels, XCD grid 512)
  gemm_o<<<dim3(512), blk, 0, stream>>>(og, WoT, bo, out);
}